// Round 1
// baseline (1751.186 us; speedup 1.0000x reference)
//
#include <hip/hip_runtime.h>

// Model: conv(32x2,s2) -> conv(32x9,s2) -> GRU encoder (105 steps) ->
//        attention decoder (63 steps) -> fc.  B=64,H=128,V=32.
// Sizes
#define TB 64
#define T1 241
#define F1 80
#define T2 105
#define F2 36
#define NC 32          // channels (conv1 out / conv2 in/out)
#define HH 128
#define G3 384         // 3*H
#define KIN 1152       // 32*36
#define VOC 32
#define LS 63          // decoder steps

typedef float f32x4 __attribute__((ext_vector_type(4)));
typedef short s16x8 __attribute__((ext_vector_type(8)));

static __device__ __forceinline__ unsigned short f2b(float f) {
  unsigned int u = __float_as_uint(f);
  unsigned int r = u + 0x7fffu + ((u >> 16) & 1u);
  return (unsigned short)(r >> 16);
}
static __device__ __forceinline__ float sigmoidf_(float x) {
  return 1.0f / (1.0f + __expf(-x));
}
static __device__ __forceinline__ float tanhf_(float x) {
  float ax = fabsf(x);
  float t = __expf(-2.0f * ax);
  float r = (1.0f - t) / (1.0f + t);
  return x >= 0.0f ? r : -r;
}

// ---------------- weight pre-transforms (re-run every launch; ws is re-poisoned) ----
// wt2[((kt*9+kf)*32+n)*32+ci] = bf16(conv2_w[n][ci][kt][kf])
// wihB = bf16(gru_w_ih) same layout [384][1152]
// wpe/wpd: packed transposed GRU hh weights: [k2=64][j=384] of (bf16 lo=w[j][2k2], hi=w[j][2k2+1])
// wdT[e*384+j] = dec_w_ih[j][e]
__global__ __launch_bounds__(256) void prep_kernel(
    const float* __restrict__ w2, const float* __restrict__ wih,
    const float* __restrict__ whh, const float* __restrict__ dwhh,
    const float* __restrict__ dwih,
    unsigned short* __restrict__ wt2, unsigned short* __restrict__ wihB,
    unsigned int* __restrict__ wpe, unsigned int* __restrict__ wpd,
    float* __restrict__ wdT) {
  int idx = blockIdx.x * 256 + threadIdx.x;
  if (idx < 294912) {
    int ci = idx & 31;
    int n = (idx >> 5) & 31;
    int kk = idx >> 10;          // kt*9+kf
    int kf = kk % 9, kt = kk / 9;
    wt2[idx] = f2b(w2[((n * 32 + ci) * 32 + kt) * 9 + kf]);
  } else if (idx < 737280) {     // 294912+442368
    int i = idx - 294912;
    wihB[i] = f2b(wih[i]);
  } else if (idx < 761856) {
    int i = idx - 737280;
    int j = i % 384, k2 = i / 384;
    unsigned int lo = f2b(whh[j * 128 + 2 * k2]);
    unsigned int hi = f2b(whh[j * 128 + 2 * k2 + 1]);
    wpe[i] = lo | (hi << 16);
  } else if (idx < 786432) {
    int i = idx - 761856;
    int j = i % 384, k2 = i / 384;
    unsigned int lo = f2b(dwhh[j * 128 + 2 * k2]);
    unsigned int hi = f2b(dwhh[j * 128 + 2 * k2 + 1]);
    wpd[i] = lo | (hi << 16);
  } else if (idx < 798720) {
    int i = idx - 786432;
    int j = i % 384, e = i / 384;
    wdT[i] = dwih[j * 32 + e];
  }
}

// ---------------- conv1: (x-mean)/std -> conv 32x2 s2 + relu, out [b][t][f][c] bf16 --
__global__ __launch_bounds__(256) void conv1_kernel(
    const float* __restrict__ x, const float* __restrict__ mean,
    const float* __restrict__ stdv, const float* __restrict__ w1,
    const float* __restrict__ b1, unsigned short* __restrict__ c1out) {
  __shared__ float ins[32][162];
  __shared__ float meanL[161];
  __shared__ float rstdL[161];
  int tid = threadIdx.x;
  int bid = blockIdx.x;
  int b = bid / 241, t = bid - b * 241;
  if (tid < 161) {
    meanL[tid] = mean[tid];
    rstdL[tid] = 1.0f / stdv[tid];
  }
  int c = tid & 31;
  float wreg[64];
  {
    const float4* wv = (const float4*)(w1 + c * 64);
#pragma unroll
    for (int i = 0; i < 16; ++i) {
      float4 v = wv[i];
      wreg[4 * i] = v.x; wreg[4 * i + 1] = v.y;
      wreg[4 * i + 2] = v.z; wreg[4 * i + 3] = v.w;
    }
  }
  float bias = b1[c];
  __syncthreads();
  const float* xrow = x + ((size_t)b * 512 + 2 * t) * 161;
  for (int i = tid; i < 32 * 161; i += 256) {
    int r = i / 161, col = i - r * 161;
    ins[r][col] = (xrow[(size_t)r * 161 + col] - meanL[col]) * rstdL[col];
  }
  __syncthreads();
  int fh = tid >> 5;
  unsigned short* orow = c1out + ((size_t)bid * 80) * 32 + c;
#pragma unroll
  for (int i = 0; i < 10; ++i) {
    int f = fh + 8 * i;
    float acc = bias;
#pragma unroll
    for (int kt = 0; kt < 32; ++kt) {
      float2 v = *(const float2*)&ins[kt][2 * f];
      acc = fmaf(v.x, wreg[2 * kt], acc);
      acc = fmaf(v.y, wreg[2 * kt + 1], acc);
    }
    acc = acc > 0.0f ? acc : 0.0f;
    orow[(size_t)f * 32] = f2b(acc);
  }
}

// ---------------- conv2: implicit GEMM, M=241920 (b,t2,f2), N=32, K=9216 -------------
// out written as X2[b][t2][c][f2] bf16 (= GRU-input reshape layout)
__global__ __launch_bounds__(256) void conv2_kernel(
    const unsigned short* __restrict__ c1out, const unsigned short* __restrict__ wt2,
    const float* __restrict__ b2, unsigned short* __restrict__ X2) {
  int tid = threadIdx.x;
  int lane = tid & 63, wave = tid >> 6;
  int quad = lane >> 4, l16 = lane & 15;
  int m_base = blockIdx.x * 256 + wave * 64;
  const unsigned short* ap[4];
#pragma unroll
  for (int mt = 0; mt < 4; ++mt) {
    int m = m_base + mt * 16 + l16;
    int b = m / 3780;
    int rm = m - b * 3780;
    int t2 = rm / 36, f2 = rm - (rm / 36) * 36;
    ap[mt] = c1out + ((size_t)((b * 241 + 2 * t2) * 80 + 2 * f2)) * 32 + quad * 8;
  }
  const unsigned short* bp = wt2 + l16 * 32 + quad * 8;
  f32x4 zero = {0.f, 0.f, 0.f, 0.f};
  f32x4 acc[4][2];
#pragma unroll
  for (int mt = 0; mt < 4; ++mt) {
    acc[mt][0] = zero;
    acc[mt][1] = zero;
  }
  for (int kt = 0; kt < 32; ++kt) {
    const unsigned short* bk = bp + kt * 9216;
#pragma unroll
    for (int kf = 0; kf < 9; ++kf) {
      s16x8 b0 = *(const s16x8*)(bk + kf * 1024);
      s16x8 b1v = *(const s16x8*)(bk + kf * 1024 + 512);
      int aoff = (kt * 80 + kf) * 32;
#pragma unroll
      for (int mt = 0; mt < 4; ++mt) {
        s16x8 a = *(const s16x8*)(ap[mt] + aoff);
        acc[mt][0] = __builtin_amdgcn_mfma_f32_16x16x32_bf16(a, b0, acc[mt][0], 0, 0, 0);
        acc[mt][1] = __builtin_amdgcn_mfma_f32_16x16x32_bf16(a, b1v, acc[mt][1], 0, 0, 0);
      }
    }
  }
#pragma unroll
  for (int nt = 0; nt < 2; ++nt) {
    int n = nt * 16 + l16;
    float bias = b2[n];
#pragma unroll
    for (int mt = 0; mt < 4; ++mt) {
      f32x4 v = acc[mt][nt];
#pragma unroll
      for (int r = 0; r < 4; ++r) {
        int m = m_base + mt * 16 + quad * 4 + r;
        int b = m / 3780;
        int rm = m - b * 3780;
        int t2 = rm / 36, f2 = rm - (rm / 36) * 36;
        float val = v[r] + bias;
        val = val > 0.0f ? val : 0.0f;
        X2[((size_t)(b * 105 + t2) * 32 + n) * 36 + f2] = f2b(val);
      }
    }
  }
}

// ---------------- xp GEMM: xp[(b,t2)][j] = X2 @ w_ih^T + b_ih, M=6720,N=384,K=1152 ---
__global__ __launch_bounds__(256) void xp_kernel(
    const unsigned short* __restrict__ X2, const unsigned short* __restrict__ wihB,
    const float* __restrict__ bih, float* __restrict__ xp) {
  int tid = threadIdx.x;
  int lane = tid & 63, wave = tid >> 6;
  int quad = lane >> 4, l16 = lane & 15;
  int m_tile = blockIdx.x * 4 + wave;   // 0..419
  int n0 = blockIdx.y * 128;
  int row = m_tile * 16 + l16;
  const unsigned short* apb = X2 + (size_t)row * 1152 + quad * 8;
  const unsigned short* bpb = wihB + (size_t)(n0 + l16) * 1152 + quad * 8;
  f32x4 zero = {0.f, 0.f, 0.f, 0.f};
  f32x4 acc[8];
#pragma unroll
  for (int nt = 0; nt < 8; ++nt) acc[nt] = zero;
  for (int ks = 0; ks < 36; ++ks) {
    s16x8 a = *(const s16x8*)(apb + ks * 32);
#pragma unroll
    for (int nt = 0; nt < 8; ++nt) {
      s16x8 bb = *(const s16x8*)(bpb + (size_t)nt * 16 * 1152 + ks * 32);
      acc[nt] = __builtin_amdgcn_mfma_f32_16x16x32_bf16(a, bb, acc[nt], 0, 0, 0);
    }
  }
#pragma unroll
  for (int nt = 0; nt < 8; ++nt) {
    int n = n0 + nt * 16 + l16;
    float bias = bih[n];
#pragma unroll
    for (int r = 0; r < 4; ++r) {
      int m = m_tile * 16 + quad * 4 + r;
      xp[(size_t)m * 384 + n] = acc[nt][r] + bias;
    }
  }
}

// ---------------- encoder GRU: 64 blocks (one batch each), 105 steps ----------------
__global__ __launch_bounds__(384) void enc_kernel(
    const float* __restrict__ xp, const unsigned int* __restrict__ wpe,
    const float* __restrict__ bhh, float* __restrict__ eh) {
  __shared__ float h_s[128];
  __shared__ float gh_s[384];
  int tid = threadIdx.x, b = blockIdx.x;
  if (tid < 128) h_s[tid] = 0.0f;
  float bias = bhh[tid];
  __syncthreads();
  const float* xpb = xp + (size_t)b * 105 * 384;
  for (int t = 0; t < 105; ++t) {
    float acc = bias;
#pragma unroll 8
    for (int k2 = 0; k2 < 64; ++k2) {
      unsigned int w = wpe[k2 * 384 + tid];
      float2 h2 = *(const float2*)&h_s[2 * k2];
      acc = fmaf(h2.x, __uint_as_float(w << 16), acc);
      acc = fmaf(h2.y, __uint_as_float(w & 0xffff0000u), acc);
    }
    gh_s[tid] = acc;
    __syncthreads();
    if (tid < 128) {
      const float* xpt = xpb + (size_t)t * 384;
      float xr = xpt[tid], xz = xpt[tid + 128], xn = xpt[tid + 256];
      float r = sigmoidf_(xr + acc);
      float z = sigmoidf_(xz + gh_s[tid + 128]);
      float nn = tanhf_(xn + r * gh_s[tid + 256]);
      float hn = (1.0f - z) * nn + z * h_s[tid];
      h_s[tid] = hn;
      eh[((size_t)b * 105 + t) * 128 + tid] = hn;
    }
    __syncthreads();
  }
}

// ---------------- ip: emb[y] @ dec_w_ih^T + b ---------------------------------------
__global__ __launch_bounds__(384) void ip_kernel(
    const int* __restrict__ y, const float* __restrict__ emb,
    const float* __restrict__ wdT, const float* __restrict__ dbih,
    float* __restrict__ ipg) {
  __shared__ float er[32];
  int bs = blockIdx.x;
  int b = bs / 63, s = bs - b * 63;
  int tid = threadIdx.x;
  if (tid < 32) er[tid] = emb[(size_t)y[b * 64 + s] * 32 + tid];
  __syncthreads();
  float acc = dbih[tid];
#pragma unroll
  for (int e = 0; e < 32; ++e) acc = fmaf(er[e], wdT[e * 384 + tid], acc);
  ipg[(size_t)bs * 384 + tid] = acc;
}

// ---------------- decoder: GRU + attention + fc, 64 blocks, 63 steps ----------------
__global__ __launch_bounds__(384) void dec_kernel(
    const float* __restrict__ eh, const float* __restrict__ ipg,
    const unsigned int* __restrict__ wpd, const float* __restrict__ dbhh,
    const float* __restrict__ fcw, const float* __restrict__ fcb,
    float* __restrict__ outg) {
  __shared__ float eh_s[105 * 133];   // pitch 133: 2-way LDS aliasing only (free)
  __shared__ float hx_s[128];
  __shared__ float hx2_s[128];
  __shared__ float gh_s[384];
  __shared__ float s_s[112];
  __shared__ float a_s[112];
  __shared__ float red_s[2];
  __shared__ float red2_s[256];
  int tid = threadIdx.x, b = blockIdx.x;
  for (int i = tid; i < 105 * 128; i += 384) {
    int t = i >> 7, d = i & 127;
    eh_s[t * 133 + d] = eh[((size_t)b * 105 + t) * 128 + d];
  }
  if (tid < 128) hx_s[tid] = 0.0f;
  float bias = dbhh[tid];
  __syncthreads();
  for (int s = 0; s < 63; ++s) {
    float acc = bias;
#pragma unroll 8
    for (int k2 = 0; k2 < 64; ++k2) {
      unsigned int w = wpd[k2 * 384 + tid];
      float2 h2 = *(const float2*)&hx_s[2 * k2];
      acc = fmaf(h2.x, __uint_as_float(w << 16), acc);
      acc = fmaf(h2.y, __uint_as_float(w & 0xffff0000u), acc);
    }
    gh_s[tid] = acc;
    __syncthreads();
    if (tid < 128) {
      const float* ipt = ipg + ((size_t)b * 63 + s) * 384;
      float xr = ipt[tid], xz = ipt[tid + 128], xn = ipt[tid + 256];
      float r = sigmoidf_(xr + acc);
      float z = sigmoidf_(xz + gh_s[tid + 128]);
      float nn = tanhf_(xn + r * gh_s[tid + 256]);
      hx2_s[tid] = (1.0f - z) * nn + z * hx_s[tid];
    }
    __syncthreads();
    if (tid < 105) {
      float sc = 0.0f;
      const float* ehrow = &eh_s[tid * 133];
#pragma unroll 8
      for (int d = 0; d < 128; ++d) sc = fmaf(ehrow[d], hx2_s[d], sc);
      s_s[tid] = sc;
    }
    __syncthreads();
    if (tid < 64) {
      float v = s_s[tid];
      if (tid + 64 < 105) v = fmaxf(v, s_s[tid + 64]);
#pragma unroll
      for (int off = 32; off > 0; off >>= 1) v = fmaxf(v, __shfl_xor(v, off));
      if (tid == 0) red_s[0] = v;
    }
    __syncthreads();
    float smax = red_s[0];
    if (tid < 105) a_s[tid] = __expf(s_s[tid] - smax);
    __syncthreads();
    if (tid < 64) {
      float v = a_s[tid] + ((tid + 64 < 105) ? a_s[tid + 64] : 0.0f);
#pragma unroll
      for (int off = 32; off > 0; off >>= 1) v += __shfl_xor(v, off);
      if (tid == 0) red_s[1] = v;
    }
    __syncthreads();
    float rsum = 1.0f / red_s[1];
    if (tid < 128) {
      float c = 0.0f;
#pragma unroll 4
      for (int t = 0; t < 105; ++t) c = fmaf(a_s[t], eh_s[t * 133 + tid], c);
      hx_s[tid] = c * rsum;   // carry = ctx
    }
    __syncthreads();
    {
      int v = tid & 31, ch = tid >> 5;
      if (ch < 8) {
        float p = 0.0f;
        const float* fw = fcw + v * 128 + ch * 16;
        const float* cx = &hx_s[ch * 16];
#pragma unroll
        for (int d2 = 0; d2 < 16; ++d2) p = fmaf(cx[d2], fw[d2], p);
        red2_s[ch * 32 + v] = p;
      }
    }
    __syncthreads();
    if (tid < 32) {
      float o = fcb[tid];
#pragma unroll
      for (int ch2 = 0; ch2 < 8; ++ch2) o += red2_s[ch2 * 32 + tid];
      outg[((size_t)b * 63 + s) * 32 + tid] = o;
    }
    __syncthreads();
  }
}

extern "C" void kernel_launch(void* const* d_in, const int* in_sizes, int n_in,
                              void* d_out, int out_size, void* d_ws, size_t ws_size,
                              hipStream_t stream) {
  const float* x = (const float*)d_in[0];
  const int* y = (const int*)d_in[1];
  const float* mean = (const float*)d_in[2];
  const float* stdv = (const float*)d_in[3];
  const float* w1 = (const float*)d_in[4];
  const float* b1 = (const float*)d_in[5];
  const float* w2 = (const float*)d_in[6];
  const float* b2 = (const float*)d_in[7];
  const float* wih = (const float*)d_in[8];
  const float* whh = (const float*)d_in[9];
  const float* bih = (const float*)d_in[10];
  const float* bhh = (const float*)d_in[11];
  const float* emb = (const float*)d_in[12];
  const float* dwih = (const float*)d_in[13];
  const float* dwhh = (const float*)d_in[14];
  const float* dbih = (const float*)d_in[15];
  const float* dbhh = (const float*)d_in[16];
  const float* fcw = (const float*)d_in[17];
  const float* fcb = (const float*)d_in[18];
  float* out = (float*)d_out;
  char* ws = (char*)d_ws;

  // ws layout (bytes); xp/eh/ip overlap dead c1out region. Total ~92 MB.
  unsigned short* c1out = (unsigned short*)(ws + 0);              // 78,970,880 B
  float* xp = (float*)(ws + 0);                                   // 10,321,920 B (after conv2)
  float* eh = (float*)(ws + 10321920);                            //  3,440,640 B
  float* ipg = (float*)(ws + 13762560);                           //  6,193,152 B
  unsigned short* wt2 = (unsigned short*)(ws + 78970880);         //    589,824 B
  unsigned short* wihB = (unsigned short*)(ws + 79560704);        //    884,736 B
  unsigned int* wpe = (unsigned int*)(ws + 80445440);             //     98,304 B
  unsigned int* wpd = (unsigned int*)(ws + 80543744);             //     98,304 B
  float* wdT = (float*)(ws + 80642048);                           //     49,152 B
  unsigned short* X2 = (unsigned short*)(ws + 80691200);          // 15,482,880 B

  prep_kernel<<<3120, 256, 0, stream>>>(w2, wih, whh, dwhh, dwih, wt2, wihB, wpe, wpd, wdT);
  conv1_kernel<<<64 * 241, 256, 0, stream>>>(x, mean, stdv, w1, b1, c1out);
  conv2_kernel<<<945, 256, 0, stream>>>(c1out, wt2, b2, X2);
  xp_kernel<<<dim3(105, 3), 256, 0, stream>>>(X2, wihB, bih, xp);
  ip_kernel<<<64 * 63, 384, 0, stream>>>(y, emb, wdT, dbih, ipg);
  enc_kernel<<<64, 384, 0, stream>>>(xp, wpe, bhh, eh);
  dec_kernel<<<64, 384, 0, stream>>>(eh, ipg, wpd, dbhh, fcw, fcb, out);
}

// Round 2
// 1321.266 us; speedup vs baseline: 1.3254x; 1.3254x over previous
//
#include <hip/hip_runtime.h>

// Model: conv(32x2,s2) -> conv(32x9,s2) -> GRU encoder (105 steps) ->
//        attention decoder (63 steps) -> fc.  B=64,H=128,V=32.

typedef float f32x4 __attribute__((ext_vector_type(4)));
typedef short s16x8 __attribute__((ext_vector_type(8)));

static __device__ __forceinline__ unsigned short f2b(float f) {
  unsigned int u = __float_as_uint(f);
  unsigned int r = u + 0x7fffu + ((u >> 16) & 1u);
  return (unsigned short)(r >> 16);
}
static __device__ __forceinline__ float sigmoidf_(float x) {
  return 1.0f / (1.0f + __expf(-x));
}
static __device__ __forceinline__ float tanhf_(float x) {
  float ax = fabsf(x);
  float t = __expf(-2.0f * ax);
  float r = (1.0f - t) / (1.0f + t);
  return x >= 0.0f ? r : -r;
}

// ---------------- weight pre-transforms (re-run every launch; ws is re-poisoned) ----
__global__ __launch_bounds__(256) void prep_kernel(
    const float* __restrict__ w2, const float* __restrict__ wih,
    const float* __restrict__ whh, const float* __restrict__ dwhh,
    const float* __restrict__ dwih,
    unsigned short* __restrict__ wt2, unsigned short* __restrict__ wihB,
    unsigned int* __restrict__ wpe, unsigned int* __restrict__ wpd,
    float* __restrict__ wdT) {
  int idx = blockIdx.x * 256 + threadIdx.x;
  if (idx < 294912) {
    int ci = idx & 31;
    int n = (idx >> 5) & 31;
    int kk = idx >> 10;          // kt*9+kf
    int kf = kk % 9, kt = kk / 9;
    wt2[idx] = f2b(w2[((n * 32 + ci) * 32 + kt) * 9 + kf]);
  } else if (idx < 737280) {
    int i = idx - 294912;
    wihB[i] = f2b(wih[i]);
  } else if (idx < 761856) {
    int i = idx - 737280;
    int j = i % 384, k2 = i / 384;
    unsigned int lo = f2b(whh[j * 128 + 2 * k2]);
    unsigned int hi = f2b(whh[j * 128 + 2 * k2 + 1]);
    wpe[i] = lo | (hi << 16);
  } else if (idx < 786432) {
    int i = idx - 761856;
    int j = i % 384, k2 = i / 384;
    unsigned int lo = f2b(dwhh[j * 128 + 2 * k2]);
    unsigned int hi = f2b(dwhh[j * 128 + 2 * k2 + 1]);
    wpd[i] = lo | (hi << 16);
  } else if (idx < 798720) {
    int i = idx - 786432;
    int j = i % 384, e = i / 384;
    wdT[i] = dwih[j * 32 + e];
  }
}

// ---------------- conv1: (x-mean)/std -> conv 32x2 s2 + relu, out [b][t][f][c] bf16 --
__global__ __launch_bounds__(256) void conv1_kernel(
    const float* __restrict__ x, const float* __restrict__ mean,
    const float* __restrict__ stdv, const float* __restrict__ w1,
    const float* __restrict__ b1, unsigned short* __restrict__ c1out) {
  __shared__ float ins[32][162];
  __shared__ float meanL[161];
  __shared__ float rstdL[161];
  int tid = threadIdx.x;
  int bid = blockIdx.x;
  int b = bid / 241, t = bid - b * 241;
  if (tid < 161) {
    meanL[tid] = mean[tid];
    rstdL[tid] = 1.0f / stdv[tid];
  }
  int c = tid & 31;
  float wreg[64];
  {
    const float4* wv = (const float4*)(w1 + c * 64);
#pragma unroll
    for (int i = 0; i < 16; ++i) {
      float4 v = wv[i];
      wreg[4 * i] = v.x; wreg[4 * i + 1] = v.y;
      wreg[4 * i + 2] = v.z; wreg[4 * i + 3] = v.w;
    }
  }
  float bias = b1[c];
  __syncthreads();
  const float* xrow = x + ((size_t)b * 512 + 2 * t) * 161;
  for (int i = tid; i < 32 * 161; i += 256) {
    int r = i / 161, col = i - r * 161;
    ins[r][col] = (xrow[(size_t)r * 161 + col] - meanL[col]) * rstdL[col];
  }
  __syncthreads();
  int fh = tid >> 5;
  unsigned short* orow = c1out + ((size_t)bid * 80) * 32 + c;
#pragma unroll
  for (int i = 0; i < 10; ++i) {
    int f = fh + 8 * i;
    float acc = bias;
#pragma unroll
    for (int kt = 0; kt < 32; ++kt) {
      float2 v = *(const float2*)&ins[kt][2 * f];
      acc = fmaf(v.x, wreg[2 * kt], acc);
      acc = fmaf(v.y, wreg[2 * kt + 1], acc);
    }
    acc = acc > 0.0f ? acc : 0.0f;
    orow[(size_t)f * 32] = f2b(acc);
  }
}

// ---------------- conv2 v2: LDS-staged implicit GEMM ------------------------------
// Block = (j=t2-tile of 7, b). Per kt: stage 7 rows x 80 f x 32 ci bf16 into LDS
// (swizzled: 16B pad after every even f-row -> uniform bank groups), then
// 9 kf x 4 mt x 2 nt MFMA from LDS fragments. Out X2[b][t2][c][f2] bf16.
__global__ __launch_bounds__(256) void conv2_kernel(
    const unsigned short* __restrict__ c1out, const unsigned short* __restrict__ wt2,
    const float* __restrict__ b2, unsigned short* __restrict__ X2) {
  // row stride per tl: 80 f-rows, row f at chunk offset 4f + (f>>1) -> 360 chunks/tl
  __shared__ int ldsA[7 * 360 * 4];   // 40,320 B
  int tid = threadIdx.x;
  int lane = tid & 63, wave = tid >> 6;
  int quad = lane >> 4, l16 = lane & 15;
  int j = blockIdx.x;       // 0..14
  int b = blockIdx.y;       // 0..63

  // per-mt read-side row base (l16-indexed rows)
  int rowbase[4];
#pragma unroll
  for (int mt = 0; mt < 4; ++mt) {
    int ml = wave * 64 + mt * 16 + l16;
    if (ml > 251) ml = 251;
    int tl = ml / 36;
    int f2 = ml - tl * 36;
    rowbase[mt] = (tl * 360 + 9 * f2 + quad) * 4;   // dword idx of chunk q at kf=0
  }
  const unsigned short* bp = wt2 + l16 * 32 + quad * 8;

  f32x4 zero = {0.f, 0.f, 0.f, 0.f};
  f32x4 acc[4][2];
#pragma unroll
  for (int mt = 0; mt < 4; ++mt) {
    acc[mt][0] = zero;
    acc[mt][1] = zero;
  }

  const size_t rowbytes = 2560;  // shorts per t-row (80*32)
  const unsigned short* gbase = c1out + ((size_t)b * 241 + 14 * j) * rowbytes;

  for (int kt = 0; kt < 32; ++kt) {
    // ---- stage A tile: 2240 chunks of 16B ----
    const unsigned short* g = gbase + (size_t)kt * rowbytes;
#pragma unroll
    for (int k = 0; k < 9; ++k) {
      int i = tid + 256 * k;
      if (i < 2240) {
        int tl = i / 320;
        int r = i - tl * 320;
        int4 v = *(const int4*)(g + (size_t)tl * 5120 + r * 8);
        *((int4*)&ldsA[(tl * 360 + r + (r >> 3)) * 4]) = v;
      }
    }
    __syncthreads();
    const unsigned short* bk = bp + kt * 9216;
#pragma unroll
    for (int kf = 0; kf < 9; ++kf) {
      s16x8 b0 = *(const s16x8*)(bk + kf * 1024);
      s16x8 b1v = *(const s16x8*)(bk + kf * 1024 + 512);
      int kfo = (4 * kf + (kf >> 1)) * 4;
#pragma unroll
      for (int mt = 0; mt < 4; ++mt) {
        s16x8 a = *(const s16x8*)&ldsA[rowbase[mt] + kfo];
        acc[mt][0] = __builtin_amdgcn_mfma_f32_16x16x32_bf16(a, b0, acc[mt][0], 0, 0, 0);
        acc[mt][1] = __builtin_amdgcn_mfma_f32_16x16x32_bf16(a, b1v, acc[mt][1], 0, 0, 0);
      }
    }
    __syncthreads();
  }

#pragma unroll
  for (int nt = 0; nt < 2; ++nt) {
    int n = nt * 16 + l16;
    float bias = b2[n];
#pragma unroll
    for (int mt = 0; mt < 4; ++mt) {
      f32x4 v = acc[mt][nt];
#pragma unroll
      for (int r = 0; r < 4; ++r) {
        int ml = wave * 64 + mt * 16 + quad * 4 + r;
        if (ml < 252) {
          int tl = ml / 36;
          int f2 = ml - tl * 36;
          int t2 = 7 * j + tl;
          float val = v[r] + bias;
          val = val > 0.0f ? val : 0.0f;
          X2[((size_t)(b * 105 + t2) * 32 + n) * 36 + f2] = f2b(val);
        }
      }
    }
  }
}

// ---------------- xp GEMM: xp[(b,t2)][j] = X2 @ w_ih^T + b_ih, M=6720,N=384,K=1152 ---
__global__ __launch_bounds__(256) void xp_kernel(
    const unsigned short* __restrict__ X2, const unsigned short* __restrict__ wihB,
    const float* __restrict__ bih, float* __restrict__ xp) {
  int tid = threadIdx.x;
  int lane = tid & 63, wave = tid >> 6;
  int quad = lane >> 4, l16 = lane & 15;
  int m_tile = blockIdx.x * 4 + wave;   // 0..419
  int n0 = blockIdx.y * 128;
  int row = m_tile * 16 + l16;
  const unsigned short* apb = X2 + (size_t)row * 1152 + quad * 8;
  const unsigned short* bpb = wihB + (size_t)(n0 + l16) * 1152 + quad * 8;
  f32x4 zero = {0.f, 0.f, 0.f, 0.f};
  f32x4 acc[8];
#pragma unroll
  for (int nt = 0; nt < 8; ++nt) acc[nt] = zero;
  for (int ks = 0; ks < 36; ++ks) {
    s16x8 a = *(const s16x8*)(apb + ks * 32);
#pragma unroll
    for (int nt = 0; nt < 8; ++nt) {
      s16x8 bb = *(const s16x8*)(bpb + (size_t)nt * 16 * 1152 + ks * 32);
      acc[nt] = __builtin_amdgcn_mfma_f32_16x16x32_bf16(a, bb, acc[nt], 0, 0, 0);
    }
  }
#pragma unroll
  for (int nt = 0; nt < 8; ++nt) {
    int n = n0 + nt * 16 + l16;
    float bias = bih[n];
#pragma unroll
    for (int r = 0; r < 4; ++r) {
      int m = m_tile * 16 + quad * 4 + r;
      xp[(size_t)m * 384 + n] = acc[nt][r] + bias;
    }
  }
}

// ---------------- encoder GRU: 64 blocks (one batch each), 105 steps ----------------
__global__ __launch_bounds__(384) void enc_kernel(
    const float* __restrict__ xp, const unsigned int* __restrict__ wpe,
    const float* __restrict__ bhh, float* __restrict__ eh) {
  __shared__ float h_s[128];
  __shared__ float gh_s[384];
  int tid = threadIdx.x, b = blockIdx.x;
  if (tid < 128) h_s[tid] = 0.0f;
  float bias = bhh[tid];
  __syncthreads();
  const float* xpb = xp + (size_t)b * 105 * 384;
  for (int t = 0; t < 105; ++t) {
    float acc = bias;
#pragma unroll 8
    for (int k2 = 0; k2 < 64; ++k2) {
      unsigned int w = wpe[k2 * 384 + tid];
      float2 h2 = *(const float2*)&h_s[2 * k2];
      acc = fmaf(h2.x, __uint_as_float(w << 16), acc);
      acc = fmaf(h2.y, __uint_as_float(w & 0xffff0000u), acc);
    }
    gh_s[tid] = acc;
    __syncthreads();
    if (tid < 128) {
      const float* xpt = xpb + (size_t)t * 384;
      float xr = xpt[tid], xz = xpt[tid + 128], xn = xpt[tid + 256];
      float r = sigmoidf_(xr + acc);
      float z = sigmoidf_(xz + gh_s[tid + 128]);
      float nn = tanhf_(xn + r * gh_s[tid + 256]);
      float hn = (1.0f - z) * nn + z * h_s[tid];
      h_s[tid] = hn;
      eh[((size_t)b * 105 + t) * 128 + tid] = hn;
    }
    __syncthreads();
  }
}

// ---------------- ip: emb[y] @ dec_w_ih^T + b ---------------------------------------
__global__ __launch_bounds__(384) void ip_kernel(
    const int* __restrict__ y, const float* __restrict__ emb,
    const float* __restrict__ wdT, const float* __restrict__ dbih,
    float* __restrict__ ipg) {
  __shared__ float er[32];
  int bs = blockIdx.x;
  int b = bs / 63, s = bs - b * 63;
  int tid = threadIdx.x;
  if (tid < 32) er[tid] = emb[(size_t)y[b * 64 + s] * 32 + tid];
  __syncthreads();
  float acc = dbih[tid];
#pragma unroll
  for (int e = 0; e < 32; ++e) acc = fmaf(er[e], wdT[e * 384 + tid], acc);
  ipg[(size_t)bs * 384 + tid] = acc;
}

// ---------------- decoder: GRU + attention + fc, 64 blocks, 63 steps ----------------
__global__ __launch_bounds__(384) void dec_kernel(
    const float* __restrict__ eh, const float* __restrict__ ipg,
    const unsigned int* __restrict__ wpd, const float* __restrict__ dbhh,
    const float* __restrict__ fcw, const float* __restrict__ fcb,
    float* __restrict__ outg) {
  __shared__ float eh_s[105 * 133];   // pitch 133: 2-way LDS aliasing only (free)
  __shared__ float hx_s[128];
  __shared__ float hx2_s[128];
  __shared__ float gh_s[384];
  __shared__ float s_s[112];
  __shared__ float a_s[112];
  __shared__ float red_s[2];
  __shared__ float red2_s[256];
  int tid = threadIdx.x, b = blockIdx.x;
  for (int i = tid; i < 105 * 128; i += 384) {
    int t = i >> 7, d = i & 127;
    eh_s[t * 133 + d] = eh[((size_t)b * 105 + t) * 128 + d];
  }
  if (tid < 128) hx_s[tid] = 0.0f;
  float bias = dbhh[tid];
  __syncthreads();
  for (int s = 0; s < 63; ++s) {
    float acc = bias;
#pragma unroll 8
    for (int k2 = 0; k2 < 64; ++k2) {
      unsigned int w = wpd[k2 * 384 + tid];
      float2 h2 = *(const float2*)&hx_s[2 * k2];
      acc = fmaf(h2.x, __uint_as_float(w << 16), acc);
      acc = fmaf(h2.y, __uint_as_float(w & 0xffff0000u), acc);
    }
    gh_s[tid] = acc;
    __syncthreads();
    if (tid < 128) {
      const float* ipt = ipg + ((size_t)b * 63 + s) * 384;
      float xr = ipt[tid], xz = ipt[tid + 128], xn = ipt[tid + 256];
      float r = sigmoidf_(xr + acc);
      float z = sigmoidf_(xz + gh_s[tid + 128]);
      float nn = tanhf_(xn + r * gh_s[tid + 256]);
      hx2_s[tid] = (1.0f - z) * nn + z * hx_s[tid];
    }
    __syncthreads();
    if (tid < 105) {
      float sc = 0.0f;
      const float* ehrow = &eh_s[tid * 133];
#pragma unroll 8
      for (int d = 0; d < 128; ++d) sc = fmaf(ehrow[d], hx2_s[d], sc);
      s_s[tid] = sc;
    }
    __syncthreads();
    if (tid < 64) {
      float v = s_s[tid];
      if (tid + 64 < 105) v = fmaxf(v, s_s[tid + 64]);
#pragma unroll
      for (int off = 32; off > 0; off >>= 1) v = fmaxf(v, __shfl_xor(v, off));
      if (tid == 0) red_s[0] = v;
    }
    __syncthreads();
    float smax = red_s[0];
    if (tid < 105) a_s[tid] = __expf(s_s[tid] - smax);
    __syncthreads();
    if (tid < 64) {
      float v = a_s[tid] + ((tid + 64 < 105) ? a_s[tid + 64] : 0.0f);
#pragma unroll
      for (int off = 32; off > 0; off >>= 1) v += __shfl_xor(v, off);
      if (tid == 0) red_s[1] = v;
    }
    __syncthreads();
    float rsum = 1.0f / red_s[1];
    if (tid < 128) {
      float c = 0.0f;
#pragma unroll 4
      for (int t = 0; t < 105; ++t) c = fmaf(a_s[t], eh_s[t * 133 + tid], c);
      hx_s[tid] = c * rsum;   // carry = ctx
    }
    __syncthreads();
    {
      int v = tid & 31, ch = tid >> 5;
      if (ch < 8) {
        float p = 0.0f;
        const float* fw = fcw + v * 128 + ch * 16;
        const float* cx = &hx_s[ch * 16];
#pragma unroll
        for (int d2 = 0; d2 < 16; ++d2) p = fmaf(cx[d2], fw[d2], p);
        red2_s[ch * 32 + v] = p;
      }
    }
    __syncthreads();
    if (tid < 32) {
      float o = fcb[tid];
#pragma unroll
      for (int ch2 = 0; ch2 < 8; ++ch2) o += red2_s[ch2 * 32 + tid];
      outg[((size_t)b * 63 + s) * 32 + tid] = o;
    }
    __syncthreads();
  }
}

extern "C" void kernel_launch(void* const* d_in, const int* in_sizes, int n_in,
                              void* d_out, int out_size, void* d_ws, size_t ws_size,
                              hipStream_t stream) {
  const float* x = (const float*)d_in[0];
  const int* y = (const int*)d_in[1];
  const float* mean = (const float*)d_in[2];
  const float* stdv = (const float*)d_in[3];
  const float* w1 = (const float*)d_in[4];
  const float* b1 = (const float*)d_in[5];
  const float* w2 = (const float*)d_in[6];
  const float* b2 = (const float*)d_in[7];
  const float* wih = (const float*)d_in[8];
  const float* whh = (const float*)d_in[9];
  const float* bih = (const float*)d_in[10];
  const float* bhh = (const float*)d_in[11];
  const float* emb = (const float*)d_in[12];
  const float* dwih = (const float*)d_in[13];
  const float* dwhh = (const float*)d_in[14];
  const float* dbih = (const float*)d_in[15];
  const float* dbhh = (const float*)d_in[16];
  const float* fcw = (const float*)d_in[17];
  const float* fcb = (const float*)d_in[18];
  float* out = (float*)d_out;
  char* ws = (char*)d_ws;

  // ws layout (bytes); xp/eh/ip overlap dead c1out region. Total ~92 MB.
  unsigned short* c1out = (unsigned short*)(ws + 0);              // 78,970,880 B
  float* xp = (float*)(ws + 0);                                   // 10,321,920 B (after conv2)
  float* eh = (float*)(ws + 10321920);                            //  3,440,640 B
  float* ipg = (float*)(ws + 13762560);                           //  6,193,152 B
  unsigned short* wt2 = (unsigned short*)(ws + 78970880);         //    589,824 B
  unsigned short* wihB = (unsigned short*)(ws + 79560704);        //    884,736 B
  unsigned int* wpe = (unsigned int*)(ws + 80445440);             //     98,304 B
  unsigned int* wpd = (unsigned int*)(ws + 80543744);             //     98,304 B
  float* wdT = (float*)(ws + 80642048);                           //     49,152 B
  unsigned short* X2 = (unsigned short*)(ws + 80691200);          // 15,482,880 B

  prep_kernel<<<3120, 256, 0, stream>>>(w2, wih, whh, dwhh, dwih, wt2, wihB, wpe, wpd, wdT);
  conv1_kernel<<<64 * 241, 256, 0, stream>>>(x, mean, stdv, w1, b1, c1out);
  conv2_kernel<<<dim3(15, 64), 256, 0, stream>>>(c1out, wt2, b2, X2);
  xp_kernel<<<dim3(105, 3), 256, 0, stream>>>(X2, wihB, bih, xp);
  ip_kernel<<<64 * 63, 384, 0, stream>>>(y, emb, wdT, dbih, ipg);
  enc_kernel<<<64, 384, 0, stream>>>(xp, wpe, bhh, eh);
  dec_kernel<<<64, 384, 0, stream>>>(eh, ipg, wpd, dbhh, fcw, fcb, out);
}

// Round 4
// 1250.606 us; speedup vs baseline: 1.4003x; 1.0565x over previous
//
#include <hip/hip_runtime.h>

// Model: conv(32x2,s2) -> conv(32x9,s2) -> GRU encoder (105 steps) ->
//        attention decoder (63 steps) -> fc.  B=64,H=128,V=32.

typedef float f32x4 __attribute__((ext_vector_type(4)));
typedef short s16x8 __attribute__((ext_vector_type(8)));

static __device__ __forceinline__ unsigned short f2b(float f) {
  unsigned int u = __float_as_uint(f);
  unsigned int r = u + 0x7fffu + ((u >> 16) & 1u);
  return (unsigned short)(r >> 16);
}
static __device__ __forceinline__ float sigmoidf_(float x) {
  return 1.0f / (1.0f + __expf(-x));
}
static __device__ __forceinline__ float tanhf_(float x) {
  float ax = fabsf(x);
  float t = __expf(-2.0f * ax);
  float r = (1.0f - t) / (1.0f + t);
  return x >= 0.0f ? r : -r;
}

// ---------------- weight pre-transforms (re-run every launch; ws is re-poisoned) ----
__global__ __launch_bounds__(256) void prep_kernel(
    const float* __restrict__ w2, const float* __restrict__ wih,
    const float* __restrict__ whh, const float* __restrict__ dwhh,
    const float* __restrict__ dwih,
    unsigned short* __restrict__ wt2, unsigned short* __restrict__ wihB,
    unsigned int* __restrict__ wpe, unsigned int* __restrict__ wpd,
    float* __restrict__ wdT) {
  int idx = blockIdx.x * 256 + threadIdx.x;
  if (idx < 294912) {
    int ci = idx & 31;
    int n = (idx >> 5) & 31;
    int kk = idx >> 10;          // kt*9+kf
    int kf = kk % 9, kt = kk / 9;
    wt2[idx] = f2b(w2[((n * 32 + ci) * 32 + kt) * 9 + kf]);
  } else if (idx < 737280) {
    int i = idx - 294912;
    wihB[i] = f2b(wih[i]);
  } else if (idx < 761856) {
    int i = idx - 737280;
    int j = i % 384, k2 = i / 384;
    unsigned int lo = f2b(whh[j * 128 + 2 * k2]);
    unsigned int hi = f2b(whh[j * 128 + 2 * k2 + 1]);
    wpe[i] = lo | (hi << 16);
  } else if (idx < 786432) {
    int i = idx - 761856;
    int j = i % 384, k2 = i / 384;
    unsigned int lo = f2b(dwhh[j * 128 + 2 * k2]);
    unsigned int hi = f2b(dwhh[j * 128 + 2 * k2 + 1]);
    wpd[i] = lo | (hi << 16);
  } else if (idx < 798720) {
    int i = idx - 786432;
    int j = i % 384, e = i / 384;
    wdT[i] = dwih[j * 32 + e];
  }
}

// ---------------- conv1: (x-mean)/std -> conv 32x2 s2 + relu, out [b][t][f][c] bf16 --
__global__ __launch_bounds__(256) void conv1_kernel(
    const float* __restrict__ x, const float* __restrict__ mean,
    const float* __restrict__ stdv, const float* __restrict__ w1,
    const float* __restrict__ b1, unsigned short* __restrict__ c1out) {
  __shared__ float ins[32][162];
  __shared__ float meanL[161];
  __shared__ float rstdL[161];
  int tid = threadIdx.x;
  int bid = blockIdx.x;
  int b = bid / 241, t = bid - b * 241;
  if (tid < 161) {
    meanL[tid] = mean[tid];
    rstdL[tid] = 1.0f / stdv[tid];
  }
  int c = tid & 31;
  float wreg[64];
  {
    const float4* wv = (const float4*)(w1 + c * 64);
#pragma unroll
    for (int i = 0; i < 16; ++i) {
      float4 v = wv[i];
      wreg[4 * i] = v.x; wreg[4 * i + 1] = v.y;
      wreg[4 * i + 2] = v.z; wreg[4 * i + 3] = v.w;
    }
  }
  float bias = b1[c];
  __syncthreads();
  const float* xrow = x + ((size_t)b * 512 + 2 * t) * 161;
  for (int i = tid; i < 32 * 161; i += 256) {
    int r = i / 161, col = i - r * 161;
    ins[r][col] = (xrow[(size_t)r * 161 + col] - meanL[col]) * rstdL[col];
  }
  __syncthreads();
  int fh = tid >> 5;
  unsigned short* orow = c1out + ((size_t)bid * 80) * 32 + c;
#pragma unroll
  for (int i = 0; i < 10; ++i) {
    int f = fh + 8 * i;
    float acc = bias;
#pragma unroll
    for (int kt = 0; kt < 32; ++kt) {
      float2 v = *(const float2*)&ins[kt][2 * f];
      acc = fmaf(v.x, wreg[2 * kt], acc);
      acc = fmaf(v.y, wreg[2 * kt + 1], acc);
    }
    acc = acc > 0.0f ? acc : 0.0f;
    orow[(size_t)f * 32] = f2b(acc);
  }
}

// ---------------- conv2 v3: LDS ring-buffer implicit GEMM --------------------------
// Block = (j: 7 t2-rows, b). Rows needed at kt have parity of kt -> two phases
// (even kt, odd kt); rolling ring of 8 one-t-row slots; each kt stages ONE new
// row (vs 7) and needs ONE barrier. Slot written at step k ((k+6)&7) is never
// read at step k-1 (reads cover (k-1..k+5)&7), so no second barrier.
__global__ __launch_bounds__(256) void conv2_kernel(
    const unsigned short* __restrict__ c1out, const unsigned short* __restrict__ wt2,
    const float* __restrict__ b2, unsigned short* __restrict__ X2) {
  __shared__ int ldsA[8 * 360 * 4];   // 8 slots x 360 16B-chunks = 46,080 B
  int tid = threadIdx.x;
  int lane = tid & 63, wave = tid >> 6;
  int quad = lane >> 4, l16 = lane & 15;
  int j = blockIdx.x;       // 0..14
  int b = blockIdx.y;       // 0..63

  int tlA[4], baseA[4];
#pragma unroll
  for (int mt = 0; mt < 4; ++mt) {
    int ml = wave * 64 + mt * 16 + l16;
    if (ml > 251) ml = 251;
    int tl = ml / 36;
    int f2 = ml - tl * 36;
    tlA[mt] = tl;
    baseA[mt] = (9 * f2 + quad) * 4;   // dword offset within slot at kf=0
  }
  const unsigned short* bp = wt2 + l16 * 32 + quad * 8;

  f32x4 zero = {0.f, 0.f, 0.f, 0.f};
  f32x4 acc[4][2];
#pragma unroll
  for (int mt = 0; mt < 4; ++mt) {
    acc[mt][0] = zero;
    acc[mt][1] = zero;
  }

  const size_t rowsh = 2560;  // shorts per t-row (80*32)
  const unsigned short* gbase = c1out + ((size_t)b * 241 + 14 * j) * rowsh;

  for (int p = 0; p < 2; ++p) {
    // initial stage: rows h=0..6 (global row p+2h) into slots 0..6
#pragma unroll
    for (int k = 0; k < 9; ++k) {
      int i = tid + 256 * k;
      if (i < 2240) {
        int h = i / 320, r = i - 320 * h;
        int4 v = *(const int4*)(gbase + (size_t)(p + 2 * h) * rowsh + r * 8);
        *((int4*)&ldsA[(h * 360 + r + (r >> 3)) * 4]) = v;
      }
    }
    for (int k = 0; k < 16; ++k) {
      int kt = 2 * k + p;
      if (k > 0) {
        int slot = (k + 6) & 7;
        const unsigned short* g = gbase + (size_t)(p + 2 * (k + 6)) * rowsh;
        int r = tid;
        int4 v = *(const int4*)(g + r * 8);
        *((int4*)&ldsA[(slot * 360 + r + (r >> 3)) * 4]) = v;
        if (tid < 64) {
          int r2 = 256 + tid;
          int4 v2 = *(const int4*)(g + r2 * 8);
          *((int4*)&ldsA[(slot * 360 + r2 + (r2 >> 3)) * 4]) = v2;
        }
      }
      __syncthreads();
      const unsigned short* bk = bp + (size_t)kt * 9216;
#pragma unroll
      for (int kf = 0; kf < 9; ++kf) {
        s16x8 b0 = *(const s16x8*)(bk + kf * 1024);
        s16x8 b1v = *(const s16x8*)(bk + kf * 1024 + 512);
        int kfo = (4 * kf + (kf >> 1)) * 4;
#pragma unroll
        for (int mt = 0; mt < 4; ++mt) {
          int slot = (k + tlA[mt]) & 7;
          s16x8 a = *(const s16x8*)&ldsA[slot * 1440 + baseA[mt] + kfo];
          acc[mt][0] = __builtin_amdgcn_mfma_f32_16x16x32_bf16(a, b0, acc[mt][0], 0, 0, 0);
          acc[mt][1] = __builtin_amdgcn_mfma_f32_16x16x32_bf16(a, b1v, acc[mt][1], 0, 0, 0);
        }
      }
    }
    __syncthreads();   // protect ring before next phase's initial restage
  }

#pragma unroll
  for (int nt = 0; nt < 2; ++nt) {
    int n = nt * 16 + l16;
    float bias = b2[n];
#pragma unroll
    for (int mt = 0; mt < 4; ++mt) {
      f32x4 v = acc[mt][nt];
#pragma unroll
      for (int r = 0; r < 4; ++r) {
        int ml = wave * 64 + mt * 16 + quad * 4 + r;
        if (ml < 252) {
          int tl = ml / 36;
          int f2 = ml - tl * 36;
          int t2 = 7 * j + tl;
          float val = v[r] + bias;
          val = val > 0.0f ? val : 0.0f;
          X2[((size_t)(b * 105 + t2) * 32 + n) * 36 + f2] = f2b(val);
        }
      }
    }
  }
}

// ---------------- xp GEMM: xp[(b,t2)][j] = X2 @ w_ih^T + b_ih, M=6720,N=384,K=1152 ---
__global__ __launch_bounds__(256) void xp_kernel(
    const unsigned short* __restrict__ X2, const unsigned short* __restrict__ wihB,
    const float* __restrict__ bih, float* __restrict__ xp) {
  int tid = threadIdx.x;
  int lane = tid & 63, wave = tid >> 6;
  int quad = lane >> 4, l16 = lane & 15;
  int m_tile = blockIdx.x * 4 + wave;   // 0..419
  int n0 = blockIdx.y * 128;
  int row = m_tile * 16 + l16;
  const unsigned short* apb = X2 + (size_t)row * 1152 + quad * 8;
  const unsigned short* bpb = wihB + (size_t)(n0 + l16) * 1152 + quad * 8;
  f32x4 zero = {0.f, 0.f, 0.f, 0.f};
  f32x4 acc[8];
#pragma unroll
  for (int nt = 0; nt < 8; ++nt) acc[nt] = zero;
  for (int ks = 0; ks < 36; ++ks) {
    s16x8 a = *(const s16x8*)(apb + ks * 32);
#pragma unroll
    for (int nt = 0; nt < 8; ++nt) {
      s16x8 bb = *(const s16x8*)(bpb + (size_t)nt * 16 * 1152 + ks * 32);
      acc[nt] = __builtin_amdgcn_mfma_f32_16x16x32_bf16(a, bb, acc[nt], 0, 0, 0);
    }
  }
#pragma unroll
  for (int nt = 0; nt < 8; ++nt) {
    int n = n0 + nt * 16 + l16;
    float bias = bih[n];
#pragma unroll
    for (int r = 0; r < 4; ++r) {
      int m = m_tile * 16 + quad * 4 + r;
      xp[(size_t)m * 384 + n] = acc[nt][r] + bias;
    }
  }
}

// ---------------- encoder GRU: 64 blocks (one batch each), 105 steps ----------------
// w_hh register-resident (64 packed bf16x2 per thread).
__global__ __launch_bounds__(384) void enc_kernel(
    const float* __restrict__ xp, const unsigned int* __restrict__ wpe,
    const float* __restrict__ bhh, float* __restrict__ eh) {
  __shared__ float h_s[128];
  __shared__ float gh_s[384];
  int tid = threadIdx.x, b = blockIdx.x;
  unsigned int w[64];
#pragma unroll
  for (int k2 = 0; k2 < 64; ++k2) w[k2] = wpe[k2 * 384 + tid];
  if (tid < 128) h_s[tid] = 0.0f;
  float bias = bhh[tid];
  __syncthreads();
  const float* xpb = xp + (size_t)b * 105 * 384;
  for (int t = 0; t < 105; ++t) {
    float acc = bias;
#pragma unroll
    for (int k2 = 0; k2 < 64; ++k2) {
      unsigned int wv = w[k2];
      float2 h2 = *(const float2*)&h_s[2 * k2];
      acc = fmaf(h2.x, __uint_as_float(wv << 16), acc);
      acc = fmaf(h2.y, __uint_as_float(wv & 0xffff0000u), acc);
    }
    gh_s[tid] = acc;
    __syncthreads();
    if (tid < 128) {
      const float* xpt = xpb + (size_t)t * 384;
      float xr = xpt[tid], xz = xpt[tid + 128], xn = xpt[tid + 256];
      float r = sigmoidf_(xr + acc);
      float z = sigmoidf_(xz + gh_s[tid + 128]);
      float nn = tanhf_(xn + r * gh_s[tid + 256]);
      float hn = (1.0f - z) * nn + z * h_s[tid];
      h_s[tid] = hn;
      eh[((size_t)b * 105 + t) * 128 + tid] = hn;
    }
    __syncthreads();
  }
}

// ---------------- ip: emb[y] @ dec_w_ih^T + b ---------------------------------------
__global__ __launch_bounds__(384) void ip_kernel(
    const int* __restrict__ y, const float* __restrict__ emb,
    const float* __restrict__ wdT, const float* __restrict__ dbih,
    float* __restrict__ ipg) {
  __shared__ float er[32];
  int bs = blockIdx.x;
  int b = bs / 63, s = bs - b * 63;
  int tid = threadIdx.x;
  if (tid < 32) er[tid] = emb[(size_t)y[b * 64 + s] * 32 + tid];
  __syncthreads();
  float acc = dbih[tid];
#pragma unroll
  for (int e = 0; e < 32; ++e) acc = fmaf(er[e], wdT[e * 384 + tid], acc);
  ipg[(size_t)bs * 384 + tid] = acc;
}

// ---------------- decoder v2: 128 threads, w_hh in VGPRs, 5 barriers/step -----------
__global__ __launch_bounds__(128) void dec_kernel(
    const float* __restrict__ eh, const float* __restrict__ ipg,
    const unsigned int* __restrict__ wpd, const float* __restrict__ dbhh,
    const float* __restrict__ fcw, const float* __restrict__ fcb,
    float* __restrict__ outg) {
  __shared__ float eh_s[105 * 132];   // pitch 132 (16B aligned rows -> b128 reads)
  __shared__ float hx_s[128];
  __shared__ float hx2_s[128];
  __shared__ float a_s[105];
  __shared__ float redm[2];
  __shared__ float reds[2];
  __shared__ float red2_s[128];
  int tid = threadIdx.x, b = blockIdx.x;
  int lane = tid & 63, wv = tid >> 6;

  // register-resident w_hh rows tid, tid+128, tid+256 (packed bf16x2)
  unsigned int w0[64], w1[64], w2[64];
#pragma unroll
  for (int k2 = 0; k2 < 64; ++k2) {
    w0[k2] = wpd[k2 * 384 + tid];
    w1[k2] = wpd[k2 * 384 + 128 + tid];
    w2[k2] = wpd[k2 * 384 + 256 + tid];
  }
  float br = dbhh[tid], bz = dbhh[tid + 128], bn = dbhh[tid + 256];

  for (int i = tid; i < 105 * 128; i += 128) {
    int t = i >> 7;
    eh_s[t * 132 + tid] = eh[((size_t)b * 105 + t) * 128 + tid];
  }
  hx_s[tid] = 0.0f;
  __syncthreads();

  const float* ipb = ipg + (size_t)b * 63 * 384;
  for (int s = 0; s < 63; ++s) {
    // ---- A: hh GEMV (3 gates) + gate math -> hx2 ----
    float ar = br, az = bz, an = bn;
#pragma unroll
    for (int k2 = 0; k2 < 64; ++k2) {
      float2 h2 = *(const float2*)&hx_s[2 * k2];
      unsigned int vr = w0[k2], vz = w1[k2], vn = w2[k2];
      ar = fmaf(h2.x, __uint_as_float(vr << 16), ar);
      ar = fmaf(h2.y, __uint_as_float(vr & 0xffff0000u), ar);
      az = fmaf(h2.x, __uint_as_float(vz << 16), az);
      az = fmaf(h2.y, __uint_as_float(vz & 0xffff0000u), az);
      an = fmaf(h2.x, __uint_as_float(vn << 16), an);
      an = fmaf(h2.y, __uint_as_float(vn & 0xffff0000u), an);
    }
    const float* ipt = ipb + (size_t)s * 384;
    float r = sigmoidf_(ipt[tid] + ar);
    float z = sigmoidf_(ipt[tid + 128] + az);
    float nn = tanhf_(ipt[tid + 256] + r * an);   // FIX: n = tanh(xn + r*hn)
    float hx2 = (1.0f - z) * nn + z * hx_s[tid];
    hx2_s[tid] = hx2;
    __syncthreads();                       // (1) hx2 ready

    // ---- C: scores (105 rows; sc stays in register) ----
    float sc = -1e30f;
    if (tid < 105) {
      sc = 0.0f;
      const float* ehrow = &eh_s[tid * 132];
#pragma unroll 8
      for (int d4 = 0; d4 < 32; ++d4) {
        float4 e4 = *(const float4*)&ehrow[4 * d4];
        float4 h4 = *(const float4*)&hx2_s[4 * d4];
        sc = fmaf(e4.x, h4.x, fmaf(e4.y, h4.y, fmaf(e4.z, h4.z, fmaf(e4.w, h4.w, sc))));
      }
    }
    // ---- softmax max (wave reduce) ----
    float v = sc;
#pragma unroll
    for (int off = 32; off > 0; off >>= 1) v = fmaxf(v, __shfl_xor(v, off));
    if (lane == 0) redm[wv] = v;
    __syncthreads();                       // (2) max parts ready
    float smax = fmaxf(redm[0], redm[1]);
    float e = 0.0f;
    if (tid < 105) {
      e = __expf(sc - smax);
      a_s[tid] = e;
    }
    float sum = e;
#pragma unroll
    for (int off = 32; off > 0; off >>= 1) sum += __shfl_xor(sum, off);
    if (lane == 0) reds[wv] = sum;
    __syncthreads();                       // (3) a_s + sum parts ready
    float rsum = 1.0f / (reds[0] + reds[1]);

    // ---- ctx -> hx ----
    float c = 0.0f;
#pragma unroll 4
    for (int t = 0; t < 105; ++t) c = fmaf(a_s[t], eh_s[t * 132 + tid], c);
    hx_s[tid] = c * rsum;
    __syncthreads();                       // (4) hx (ctx) ready

    // ---- fc: out[v] = <ctx, fcw[v]> + b ----
    {
      int v_ = tid & 31, ch = tid >> 5;
      float p = 0.0f;
      const float* fw = fcw + v_ * 128 + ch * 32;
      const float* cx = &hx_s[ch * 32];
#pragma unroll
      for (int d = 0; d < 32; ++d) p = fmaf(cx[d], fw[d], p);
      red2_s[tid] = p;
    }
    __syncthreads();                       // (5) fc partials ready
    if (tid < 32) {
      float o = fcb[tid] + red2_s[tid] + red2_s[tid + 32] + red2_s[tid + 64] + red2_s[tid + 96];
      outg[((size_t)b * 63 + s) * 32 + tid] = o;
    }
  }
}

extern "C" void kernel_launch(void* const* d_in, const int* in_sizes, int n_in,
                              void* d_out, int out_size, void* d_ws, size_t ws_size,
                              hipStream_t stream) {
  const float* x = (const float*)d_in[0];
  const int* y = (const int*)d_in[1];
  const float* mean = (const float*)d_in[2];
  const float* stdv = (const float*)d_in[3];
  const float* w1 = (const float*)d_in[4];
  const float* b1 = (const float*)d_in[5];
  const float* w2 = (const float*)d_in[6];
  const float* b2 = (const float*)d_in[7];
  const float* wih = (const float*)d_in[8];
  const float* whh = (const float*)d_in[9];
  const float* bih = (const float*)d_in[10];
  const float* bhh = (const float*)d_in[11];
  const float* emb = (const float*)d_in[12];
  const float* dwih = (const float*)d_in[13];
  const float* dwhh = (const float*)d_in[14];
  const float* dbih = (const float*)d_in[15];
  const float* dbhh = (const float*)d_in[16];
  const float* fcw = (const float*)d_in[17];
  const float* fcb = (const float*)d_in[18];
  float* out = (float*)d_out;
  char* ws = (char*)d_ws;

  // ws layout (bytes); xp/eh/ip overlap dead c1out region (xp runs after conv2).
  unsigned short* c1out = (unsigned short*)(ws + 0);              // 78,970,880 B
  float* xp = (float*)(ws + 0);                                   // 10,321,920 B (after conv2)
  float* eh = (float*)(ws + 10321920);                            //  3,440,640 B
  float* ipg = (float*)(ws + 13762560);                           //  6,193,152 B
  unsigned short* wt2 = (unsigned short*)(ws + 78970880);         //    589,824 B
  unsigned short* wihB = (unsigned short*)(ws + 79560704);        //    884,736 B
  unsigned int* wpe = (unsigned int*)(ws + 80445440);             //     98,304 B
  unsigned int* wpd = (unsigned int*)(ws + 80543744);             //     98,304 B
  float* wdT = (float*)(ws + 80642048);                           //     49,152 B
  unsigned short* X2 = (unsigned short*)(ws + 80691200);          // 15,482,880 B

  prep_kernel<<<3120, 256, 0, stream>>>(w2, wih, whh, dwhh, dwih, wt2, wihB, wpe, wpd, wdT);
  conv1_kernel<<<64 * 241, 256, 0, stream>>>(x, mean, stdv, w1, b1, c1out);
  conv2_kernel<<<dim3(15, 64), 256, 0, stream>>>(c1out, wt2, b2, X2);
  xp_kernel<<<dim3(105, 3), 256, 0, stream>>>(X2, wihB, bih, xp);
  ip_kernel<<<64 * 63, 384, 0, stream>>>(y, emb, wdT, dbih, ipg);
  enc_kernel<<<64, 384, 0, stream>>>(xp, wpe, bhh, eh);
  dec_kernel<<<64, 128, 0, stream>>>(eh, ipg, wpd, dbhh, fcw, fcb, out);
}

// Round 5
// 1058.530 us; speedup vs baseline: 1.6544x; 1.1815x over previous
//
#include <hip/hip_runtime.h>

// Model: conv(32x2,s2) -> conv(32x9,s2) -> GRU encoder (105 steps) ->
//        attention decoder (63 steps) -> fc.  B=64,H=128,V=32.

typedef float f32x4 __attribute__((ext_vector_type(4)));
typedef short s16x8 __attribute__((ext_vector_type(8)));

static __device__ __forceinline__ unsigned short f2b(float f) {
  unsigned int u = __float_as_uint(f);
  unsigned int r = u + 0x7fffu + ((u >> 16) & 1u);
  return (unsigned short)(r >> 16);
}
static __device__ __forceinline__ float sigmoidf_(float x) {
  return 1.0f / (1.0f + __expf(-x));
}
static __device__ __forceinline__ float tanhf_(float x) {
  float ax = fabsf(x);
  float t = __expf(-2.0f * ax);
  float r = (1.0f - t) / (1.0f + t);
  return x >= 0.0f ? r : -r;
}

// ---------------- weight pre-transforms (re-run every launch; ws is re-poisoned) ----
__global__ __launch_bounds__(256) void prep_kernel(
    const float* __restrict__ w2, const float* __restrict__ wih,
    const float* __restrict__ whh, const float* __restrict__ dwhh,
    const float* __restrict__ dwih,
    unsigned short* __restrict__ wt2, unsigned short* __restrict__ wihB,
    unsigned int* __restrict__ wpe, unsigned int* __restrict__ wpd,
    float* __restrict__ wdT) {
  int idx = blockIdx.x * 256 + threadIdx.x;
  if (idx < 294912) {
    int ci = idx & 31;
    int n = (idx >> 5) & 31;
    int kk = idx >> 10;          // kt*9+kf
    int kf = kk % 9, kt = kk / 9;
    wt2[idx] = f2b(w2[((n * 32 + ci) * 32 + kt) * 9 + kf]);
  } else if (idx < 737280) {
    int i = idx - 294912;
    wihB[i] = f2b(wih[i]);
  } else if (idx < 761856) {
    int i = idx - 737280;
    int j = i % 384, k2 = i / 384;
    unsigned int lo = f2b(whh[j * 128 + 2 * k2]);
    unsigned int hi = f2b(whh[j * 128 + 2 * k2 + 1]);
    wpe[i] = lo | (hi << 16);
  } else if (idx < 786432) {
    int i = idx - 761856;
    int j = i % 384, k2 = i / 384;
    unsigned int lo = f2b(dwhh[j * 128 + 2 * k2]);
    unsigned int hi = f2b(dwhh[j * 128 + 2 * k2 + 1]);
    wpd[i] = lo | (hi << 16);
  } else if (idx < 798720) {
    int i = idx - 786432;
    int j = i % 384, e = i / 384;
    wdT[i] = dwih[j * 32 + e];
  }
}

// ---------------- conv1: (x-mean)/std -> conv 32x2 s2 + relu, out [b][t][f][c] bf16 --
__global__ __launch_bounds__(256) void conv1_kernel(
    const float* __restrict__ x, const float* __restrict__ mean,
    const float* __restrict__ stdv, const float* __restrict__ w1,
    const float* __restrict__ b1, unsigned short* __restrict__ c1out) {
  __shared__ float ins[32][162];
  __shared__ float meanL[161];
  __shared__ float rstdL[161];
  int tid = threadIdx.x;
  int bid = blockIdx.x;
  int b = bid / 241, t = bid - b * 241;
  if (tid < 161) {
    meanL[tid] = mean[tid];
    rstdL[tid] = 1.0f / stdv[tid];
  }
  int c = tid & 31;
  float wreg[64];
  {
    const float4* wv = (const float4*)(w1 + c * 64);
#pragma unroll
    for (int i = 0; i < 16; ++i) {
      float4 v = wv[i];
      wreg[4 * i] = v.x; wreg[4 * i + 1] = v.y;
      wreg[4 * i + 2] = v.z; wreg[4 * i + 3] = v.w;
    }
  }
  float bias = b1[c];
  __syncthreads();
  const float* xrow = x + ((size_t)b * 512 + 2 * t) * 161;
  for (int i = tid; i < 32 * 161; i += 256) {
    int r = i / 161, col = i - r * 161;
    ins[r][col] = (xrow[(size_t)r * 161 + col] - meanL[col]) * rstdL[col];
  }
  __syncthreads();
  int fh = tid >> 5;
  unsigned short* orow = c1out + ((size_t)bid * 80) * 32 + c;
#pragma unroll
  for (int i = 0; i < 10; ++i) {
    int f = fh + 8 * i;
    float acc = bias;
#pragma unroll
    for (int kt = 0; kt < 32; ++kt) {
      float2 v = *(const float2*)&ins[kt][2 * f];
      acc = fmaf(v.x, wreg[2 * kt], acc);
      acc = fmaf(v.y, wreg[2 * kt + 1], acc);
    }
    acc = acc > 0.0f ? acc : 0.0f;
    orow[(size_t)f * 32] = f2b(acc);
  }
}

// ---------------- conv2 v3: LDS ring-buffer implicit GEMM --------------------------
__global__ __launch_bounds__(256) void conv2_kernel(
    const unsigned short* __restrict__ c1out, const unsigned short* __restrict__ wt2,
    const float* __restrict__ b2, unsigned short* __restrict__ X2) {
  __shared__ int ldsA[8 * 360 * 4];   // 8 slots x 360 16B-chunks = 46,080 B
  int tid = threadIdx.x;
  int lane = tid & 63, wave = tid >> 6;
  int quad = lane >> 4, l16 = lane & 15;
  int j = blockIdx.x;       // 0..14
  int b = blockIdx.y;       // 0..63

  int tlA[4], baseA[4];
#pragma unroll
  for (int mt = 0; mt < 4; ++mt) {
    int ml = wave * 64 + mt * 16 + l16;
    if (ml > 251) ml = 251;
    int tl = ml / 36;
    int f2 = ml - tl * 36;
    tlA[mt] = tl;
    baseA[mt] = (9 * f2 + quad) * 4;   // dword offset within slot at kf=0
  }
  const unsigned short* bp = wt2 + l16 * 32 + quad * 8;

  f32x4 zero = {0.f, 0.f, 0.f, 0.f};
  f32x4 acc[4][2];
#pragma unroll
  for (int mt = 0; mt < 4; ++mt) {
    acc[mt][0] = zero;
    acc[mt][1] = zero;
  }

  const size_t rowsh = 2560;  // shorts per t-row (80*32)
  const unsigned short* gbase = c1out + ((size_t)b * 241 + 14 * j) * rowsh;

  for (int p = 0; p < 2; ++p) {
#pragma unroll
    for (int k = 0; k < 9; ++k) {
      int i = tid + 256 * k;
      if (i < 2240) {
        int h = i / 320, r = i - 320 * h;
        int4 v = *(const int4*)(gbase + (size_t)(p + 2 * h) * rowsh + r * 8);
        *((int4*)&ldsA[(h * 360 + r + (r >> 3)) * 4]) = v;
      }
    }
    for (int k = 0; k < 16; ++k) {
      int kt = 2 * k + p;
      if (k > 0) {
        int slot = (k + 6) & 7;
        const unsigned short* g = gbase + (size_t)(p + 2 * (k + 6)) * rowsh;
        int r = tid;
        int4 v = *(const int4*)(g + r * 8);
        *((int4*)&ldsA[(slot * 360 + r + (r >> 3)) * 4]) = v;
        if (tid < 64) {
          int r2 = 256 + tid;
          int4 v2 = *(const int4*)(g + r2 * 8);
          *((int4*)&ldsA[(slot * 360 + r2 + (r2 >> 3)) * 4]) = v2;
        }
      }
      __syncthreads();
      const unsigned short* bk = bp + (size_t)kt * 9216;
#pragma unroll
      for (int kf = 0; kf < 9; ++kf) {
        s16x8 b0 = *(const s16x8*)(bk + kf * 1024);
        s16x8 b1v = *(const s16x8*)(bk + kf * 1024 + 512);
        int kfo = (4 * kf + (kf >> 1)) * 4;
#pragma unroll
        for (int mt = 0; mt < 4; ++mt) {
          int slot = (k + tlA[mt]) & 7;
          s16x8 a = *(const s16x8*)&ldsA[slot * 1440 + baseA[mt] + kfo];
          acc[mt][0] = __builtin_amdgcn_mfma_f32_16x16x32_bf16(a, b0, acc[mt][0], 0, 0, 0);
          acc[mt][1] = __builtin_amdgcn_mfma_f32_16x16x32_bf16(a, b1v, acc[mt][1], 0, 0, 0);
        }
      }
    }
    __syncthreads();
  }

#pragma unroll
  for (int nt = 0; nt < 2; ++nt) {
    int n = nt * 16 + l16;
    float bias = b2[n];
#pragma unroll
    for (int mt = 0; mt < 4; ++mt) {
      f32x4 v = acc[mt][nt];
#pragma unroll
      for (int r = 0; r < 4; ++r) {
        int ml = wave * 64 + mt * 16 + quad * 4 + r;
        if (ml < 252) {
          int tl = ml / 36;
          int f2 = ml - tl * 36;
          int t2 = 7 * j + tl;
          float val = v[r] + bias;
          val = val > 0.0f ? val : 0.0f;
          X2[((size_t)(b * 105 + t2) * 32 + n) * 36 + f2] = f2b(val);
        }
      }
    }
  }
}

// ---------------- xp GEMM: xp[(b,t2)][j] = X2 @ w_ih^T + b_ih, M=6720,N=384,K=1152 ---
__global__ __launch_bounds__(256) void xp_kernel(
    const unsigned short* __restrict__ X2, const unsigned short* __restrict__ wihB,
    const float* __restrict__ bih, float* __restrict__ xp) {
  int tid = threadIdx.x;
  int lane = tid & 63, wave = tid >> 6;
  int quad = lane >> 4, l16 = lane & 15;
  int m_tile = blockIdx.x * 4 + wave;   // 0..419
  int n0 = blockIdx.y * 128;
  int row = m_tile * 16 + l16;
  const unsigned short* apb = X2 + (size_t)row * 1152 + quad * 8;
  const unsigned short* bpb = wihB + (size_t)(n0 + l16) * 1152 + quad * 8;
  f32x4 zero = {0.f, 0.f, 0.f, 0.f};
  f32x4 acc[8];
#pragma unroll
  for (int nt = 0; nt < 8; ++nt) acc[nt] = zero;
  for (int ks = 0; ks < 36; ++ks) {
    s16x8 a = *(const s16x8*)(apb + ks * 32);
#pragma unroll
    for (int nt = 0; nt < 8; ++nt) {
      s16x8 bb = *(const s16x8*)(bpb + (size_t)nt * 16 * 1152 + ks * 32);
      acc[nt] = __builtin_amdgcn_mfma_f32_16x16x32_bf16(a, bb, acc[nt], 0, 0, 0);
    }
  }
#pragma unroll
  for (int nt = 0; nt < 8; ++nt) {
    int n = n0 + nt * 16 + l16;
    float bias = bih[n];
#pragma unroll
    for (int r = 0; r < 4; ++r) {
      int m = m_tile * 16 + quad * 4 + r;
      xp[(size_t)m * 384 + n] = acc[nt][r] + bias;
    }
  }
}

// ---------------- encoder GRU v2: 384 thr, reg weights, prefetched xp ---------------
__global__ __launch_bounds__(384) void enc_kernel(
    const float* __restrict__ xp, const unsigned int* __restrict__ wpe,
    const float* __restrict__ bhh, float* __restrict__ eh) {
  __shared__ float h_s[128];
  __shared__ float gh_s[384];
  int tid = threadIdx.x, b = blockIdx.x;
  unsigned int w[64];
#pragma unroll
  for (int k2 = 0; k2 < 64; ++k2) w[k2] = wpe[k2 * 384 + tid];
  if (tid < 128) h_s[tid] = 0.0f;
  float bias = bhh[tid];
  __syncthreads();
  const float* xpb = xp + (size_t)b * 105 * 384;
  for (int t = 0; t < 105; ++t) {
    const float* xpt = xpb + (size_t)t * 384;
    float xg = 0.0f, xn = 0.0f;              // prefetch (hides L2 under GEMV)
    if (tid < 256) xg = xpt[tid];
    if (tid < 128) xn = xpt[tid + 256];
    float acc = bias;
#pragma unroll
    for (int k2 = 0; k2 < 64; ++k2) {
      unsigned int wv = w[k2];
      float2 h2 = *(const float2*)&h_s[2 * k2];
      acc = fmaf(h2.x, __uint_as_float(wv << 16), acc);
      acc = fmaf(h2.y, __uint_as_float(wv & 0xffff0000u), acc);
    }
    // r/z rows apply sigmoid here (wide phase); n rows pass raw hh pre-activation
    gh_s[tid] = (tid < 256) ? sigmoidf_(xg + acc) : acc;
    __syncthreads();
    if (tid < 128) {
      float r = gh_s[tid];
      float z = gh_s[tid + 128];
      float hnp = gh_s[tid + 256];
      float nn = tanhf_(xn + r * hnp);
      float hn = (1.0f - z) * nn + z * h_s[tid];
      h_s[tid] = hn;
      eh[((size_t)b * 105 + t) * 128 + tid] = hn;
    }
    __syncthreads();
  }
}

// ---------------- ip: emb[y] @ dec_w_ih^T + b ---------------------------------------
__global__ __launch_bounds__(384) void ip_kernel(
    const int* __restrict__ y, const float* __restrict__ emb,
    const float* __restrict__ wdT, const float* __restrict__ dbih,
    float* __restrict__ ipg) {
  __shared__ float er[32];
  int bs = blockIdx.x;
  int b = bs / 63, s = bs - b * 63;
  int tid = threadIdx.x;
  if (tid < 32) er[tid] = emb[(size_t)y[b * 64 + s] * 32 + tid];
  __syncthreads();
  float acc = dbih[tid];
#pragma unroll
  for (int e = 0; e < 32; ++e) acc = fmaf(er[e], wdT[e * 384 + tid], acc);
  ipg[(size_t)bs * 384 + tid] = acc;
}

// ---------------- decoder v3: 384 thr, 64 reg-weights/thr, split chains -------------
__global__ __launch_bounds__(384) void dec_kernel(
    const float* __restrict__ eh, const float* __restrict__ ipg,
    const unsigned int* __restrict__ wpd, const float* __restrict__ dbhh,
    const float* __restrict__ fcw, const float* __restrict__ fcb,
    float* __restrict__ outg) {
  __shared__ float eh_s[105 * 132];   // pitch 132: 16B-aligned rows
  __shared__ float gh_s[384];
  __shared__ float hx_s[128];
  __shared__ float hx2_s[128];
  __shared__ float s_s[112];
  __shared__ float a_s[112];
  __shared__ float red_s[2];
  int tid = threadIdx.x, b = blockIdx.x;

  unsigned int w[64];                 // w_hh row `tid` (packed bf16x2)
#pragma unroll
  for (int k2 = 0; k2 < 64; ++k2) w[k2] = wpd[k2 * 384 + tid];
  float bias = dbhh[tid];

  float wf[16];                       // fc weights: v=tid>>3, part=tid&7
  float fcbv = 0.0f;
  if (tid < 256) {
    int v = tid >> 3, part = tid & 7;
#pragma unroll
    for (int d = 0; d < 16; ++d) wf[d] = fcw[v * 128 + part * 16 + d];
    fcbv = fcb[v];
  }

  // stage eh (float4, coalesced)
  for (int i = tid; i < 105 * 32; i += 384) {
    int t = i >> 5, d4 = i & 31;
    *(float4*)&eh_s[t * 132 + d4 * 4] =
        *(const float4*)(eh + ((size_t)b * 105 + t) * 128 + d4 * 4);
  }
  if (tid < 128) hx_s[tid] = 0.0f;
  __syncthreads();

  const float* ipb = ipg + (size_t)b * 63 * 384;
  for (int s = 0; s < 63; ++s) {
    const float* ipt = ipb + (size_t)s * 384;
    float xg = 0.0f, xn = 0.0f;          // prefetch: L2 latency hides under GEMV
    if (tid < 256) xg = ipt[tid];
    if (tid < 128) xn = ipt[tid + 256];

    // ---- GEMV: gh[tid] = <hx, w_hh[tid]> + b_hh[tid] ----
    float acc = bias;
#pragma unroll
    for (int k2 = 0; k2 < 64; ++k2) {
      unsigned int wv = w[k2];
      float2 h2 = *(const float2*)&hx_s[2 * k2];
      acc = fmaf(h2.x, __uint_as_float(wv << 16), acc);
      acc = fmaf(h2.y, __uint_as_float(wv & 0xffff0000u), acc);
    }
    gh_s[tid] = (tid < 256) ? sigmoidf_(xg + acc) : acc;
    __syncthreads();                     // (1) gh ready

    // ---- gate math -> hx2 ----
    if (tid < 128) {
      float r = gh_s[tid];
      float z = gh_s[tid + 128];
      float hnp = gh_s[tid + 256];
      float nn = tanhf_(xn + r * hnp);
      hx2_s[tid] = (1.0f - z) * nn + z * hx_s[tid];
    }
    __syncthreads();                     // (2) hx2 ready

    // ---- scores: 105 rows x 2 K-parts ----
    {
      float sc = 0.0f;
      int row = tid >> 1, part = tid & 1;
      if (tid < 210) {
        const float* ehrow = &eh_s[row * 132 + part * 64];
        const float* hxp = &hx2_s[part * 64];
#pragma unroll
        for (int d4 = 0; d4 < 16; ++d4) {
          float4 e4 = *(const float4*)&ehrow[4 * d4];
          float4 h4 = *(const float4*)&hxp[4 * d4];
          sc = fmaf(e4.x, h4.x, fmaf(e4.y, h4.y, fmaf(e4.z, h4.z, fmaf(e4.w, h4.w, sc))));
        }
      }
      sc += __shfl_xor(sc, 1);
      if (tid < 210 && part == 0) s_s[row] = sc;
    }
    __syncthreads();                     // (3) s_s ready

    // ---- softmax (wave 0 only) ----
    if (tid < 64) {
      float s0 = s_s[tid];
      float s1 = (tid < 41) ? s_s[tid + 64] : -1e30f;
      float m = fmaxf(s0, s1);
#pragma unroll
      for (int off = 32; off > 0; off >>= 1) m = fmaxf(m, __shfl_xor(m, off));
      float e0 = __expf(s0 - m);
      float e1 = (tid < 41) ? __expf(s1 - m) : 0.0f;
      a_s[tid] = e0;
      if (tid < 41) a_s[tid + 64] = e1;
      float sum = e0 + e1;
#pragma unroll
      for (int off = 32; off > 0; off >>= 1) sum += __shfl_xor(sum, off);
      if (tid == 0) red_s[0] = 1.0f / sum;
    }
    __syncthreads();                     // (4) a_s + rsum ready
    float rsum = red_s[0];

    // ---- ctx: 128 d x 2 t-parts -> hx ----
    if (tid < 256) {
      int d = tid >> 1, p = tid & 1;
      int t0 = p ? 53 : 0, t1 = p ? 105 : 53;
      float c = 0.0f;
      for (int t = t0; t < t1; ++t) c = fmaf(a_s[t], eh_s[t * 132 + d], c);
      c += __shfl_xor(c, 1);
      if (p == 0) hx_s[d] = c * rsum;
    }
    __syncthreads();                     // (5) hx (ctx) ready

    // ---- fc: 32 v x 8 parts (overlaps next GEMV via ILP) ----
    if (tid < 256) {
      int part = tid & 7;
      float p = 0.0f;
      const float* cx = &hx_s[part * 16];
#pragma unroll
      for (int d = 0; d < 16; ++d) p = fmaf(cx[d], wf[d], p);
      p += __shfl_xor(p, 1);
      p += __shfl_xor(p, 2);
      p += __shfl_xor(p, 4);
      if (part == 0) outg[((size_t)b * 63 + s) * 32 + (tid >> 3)] = fcbv + p;
    }
  }
}

extern "C" void kernel_launch(void* const* d_in, const int* in_sizes, int n_in,
                              void* d_out, int out_size, void* d_ws, size_t ws_size,
                              hipStream_t stream) {
  const float* x = (const float*)d_in[0];
  const int* y = (const int*)d_in[1];
  const float* mean = (const float*)d_in[2];
  const float* stdv = (const float*)d_in[3];
  const float* w1 = (const float*)d_in[4];
  const float* b1 = (const float*)d_in[5];
  const float* w2 = (const float*)d_in[6];
  const float* b2 = (const float*)d_in[7];
  const float* wih = (const float*)d_in[8];
  const float* whh = (const float*)d_in[9];
  const float* bih = (const float*)d_in[10];
  const float* bhh = (const float*)d_in[11];
  const float* emb = (const float*)d_in[12];
  const float* dwih = (const float*)d_in[13];
  const float* dwhh = (const float*)d_in[14];
  const float* dbih = (const float*)d_in[15];
  const float* dbhh = (const float*)d_in[16];
  const float* fcw = (const float*)d_in[17];
  const float* fcb = (const float*)d_in[18];
  float* out = (float*)d_out;
  char* ws = (char*)d_ws;

  // ws layout (bytes); xp/eh/ip overlap dead c1out region (xp runs after conv2).
  unsigned short* c1out = (unsigned short*)(ws + 0);              // 78,970,880 B
  float* xp = (float*)(ws + 0);                                   // 10,321,920 B (after conv2)
  float* eh = (float*)(ws + 10321920);                            //  3,440,640 B
  float* ipg = (float*)(ws + 13762560);                           //  6,193,152 B
  unsigned short* wt2 = (unsigned short*)(ws + 78970880);         //    589,824 B
  unsigned short* wihB = (unsigned short*)(ws + 79560704);        //    884,736 B
  unsigned int* wpe = (unsigned int*)(ws + 80445440);             //     98,304 B
  unsigned int* wpd = (unsigned int*)(ws + 80543744);             //     98,304 B
  float* wdT = (float*)(ws + 80642048);                           //     49,152 B
  unsigned short* X2 = (unsigned short*)(ws + 80691200);          // 15,482,880 B

  prep_kernel<<<3120, 256, 0, stream>>>(w2, wih, whh, dwhh, dwih, wt2, wihB, wpe, wpd, wdT);
  conv1_kernel<<<64 * 241, 256, 0, stream>>>(x, mean, stdv, w1, b1, c1out);
  conv2_kernel<<<dim3(15, 64), 256, 0, stream>>>(c1out, wt2, b2, X2);
  xp_kernel<<<dim3(105, 3), 256, 0, stream>>>(X2, wihB, bih, xp);
  ip_kernel<<<64 * 63, 384, 0, stream>>>(y, emb, wdT, dbih, ipg);
  enc_kernel<<<64, 384, 0, stream>>>(xp, wpe, bhh, eh);
  dec_kernel<<<64, 384, 0, stream>>>(eh, ipg, wpd, dbhh, fcw, fcb, out);
}

// Round 6
// 999.157 us; speedup vs baseline: 1.7527x; 1.0594x over previous
//
#include <hip/hip_runtime.h>

// Model: conv(32x2,s2) -> conv(32x9,s2) -> GRU encoder (105 steps) ->
//        attention decoder (63 steps) -> fc.  B=64,H=128,V=32.

typedef float f32x4 __attribute__((ext_vector_type(4)));
typedef short s16x8 __attribute__((ext_vector_type(8)));

static __device__ __forceinline__ unsigned short f2b(float f) {
  unsigned int u = __float_as_uint(f);
  unsigned int r = u + 0x7fffu + ((u >> 16) & 1u);
  return (unsigned short)(r >> 16);
}
static __device__ __forceinline__ float sigmoidf_(float x) {
  return 1.0f / (1.0f + __expf(-x));
}
static __device__ __forceinline__ float tanhf_(float x) {
  float ax = fabsf(x);
  float t = __expf(-2.0f * ax);
  float r = (1.0f - t) / (1.0f + t);
  return x >= 0.0f ? r : -r;
}

// ---------------- weight pre-transforms (re-run every launch; ws is re-poisoned) ----
__global__ __launch_bounds__(256) void prep_kernel(
    const float* __restrict__ w2, const float* __restrict__ wih,
    const float* __restrict__ whh, const float* __restrict__ dwhh,
    const float* __restrict__ dwih,
    unsigned short* __restrict__ wt2, unsigned short* __restrict__ wihB,
    unsigned int* __restrict__ wpe, unsigned int* __restrict__ wpd,
    float* __restrict__ wdT) {
  int idx = blockIdx.x * 256 + threadIdx.x;
  if (idx < 294912) {
    int ci = idx & 31;
    int n = (idx >> 5) & 31;
    int kk = idx >> 10;          // kt*9+kf
    int kf = kk % 9, kt = kk / 9;
    wt2[idx] = f2b(w2[((n * 32 + ci) * 32 + kt) * 9 + kf]);
  } else if (idx < 737280) {
    int i = idx - 294912;
    wihB[i] = f2b(wih[i]);
  } else if (idx < 761856) {
    int i = idx - 737280;
    int j = i % 384, k2 = i / 384;
    unsigned int lo = f2b(whh[j * 128 + 2 * k2]);
    unsigned int hi = f2b(whh[j * 128 + 2 * k2 + 1]);
    wpe[i] = lo | (hi << 16);
  } else if (idx < 786432) {
    int i = idx - 761856;
    int j = i % 384, k2 = i / 384;
    unsigned int lo = f2b(dwhh[j * 128 + 2 * k2]);
    unsigned int hi = f2b(dwhh[j * 128 + 2 * k2 + 1]);
    wpd[i] = lo | (hi << 16);
  } else if (idx < 798720) {
    int i = idx - 786432;
    int j = i % 384, e = i / 384;
    wdT[i] = dwih[j * 32 + e];
  }
}

// ---------------- conv1 v2: row-reuse register-blocked, out [b][t][f][c] bf16 -------
// Block = (tt: 8 t-outputs, b). Stage 46 norm rows once (ins[46][162], 29.8 KB).
// Thread = (fs=tid>>4, cg=tid&15): channels {2cg,2cg+1} weights in regs; for each
// of 5 f and 46 rows, one b64 read feeds up to 8 t x 2 kf x 2 c = 32 FMA.
__global__ __launch_bounds__(256) void conv1_kernel(
    const float* __restrict__ x, const float* __restrict__ mean,
    const float* __restrict__ stdv, const float* __restrict__ w1,
    const float* __restrict__ b1, unsigned short* __restrict__ c1out) {
  __shared__ float ins[46][162];
  __shared__ float meanL[161];
  __shared__ float rstdL[161];
  int tid = threadIdx.x;
  int tt = blockIdx.x;        // 0..30
  int b = blockIdx.y;         // 0..63
  int t0 = tt * 8;
  if (tid < 161) {
    meanL[tid] = mean[tid];
    rstdL[tid] = 1.0f / stdv[tid];
  }
  int fs = tid >> 4, cg = tid & 15;
  int c0 = 2 * cg;
  float wA[64], wB[64];
  {
    const float4* wa = (const float4*)(w1 + c0 * 64);
    const float4* wb = (const float4*)(w1 + (c0 + 1) * 64);
#pragma unroll
    for (int i = 0; i < 16; ++i) {
      float4 va = wa[i], vb = wb[i];
      wA[4 * i] = va.x; wA[4 * i + 1] = va.y; wA[4 * i + 2] = va.z; wA[4 * i + 3] = va.w;
      wB[4 * i] = vb.x; wB[4 * i + 1] = vb.y; wB[4 * i + 2] = vb.z; wB[4 * i + 3] = vb.w;
    }
  }
  float biasA = b1[c0], biasB = b1[c0 + 1];
  __syncthreads();   // meanL/rstdL ready

  const float* xb = x + ((size_t)b * 512 + 2 * t0) * 161;
  int nrows = 512 - 2 * t0; if (nrows > 46) nrows = 46;
  for (int i = tid; i < 46 * 161; i += 256) {
    int r = i / 161, col = i - r * 161;
    float v = (r < nrows) ? xb[(size_t)r * 161 + col] : 0.0f;
    ins[r][col] = (v - meanL[col]) * rstdL[col];
  }
  __syncthreads();

  int T = 241 - t0; if (T > 8) T = 8;
#pragma unroll
  for (int fi = 0; fi < 5; ++fi) {
    int f = fs + 16 * fi;
    float accA[8], accB[8];
#pragma unroll
    for (int t = 0; t < 8; ++t) { accA[t] = biasA; accB[t] = biasB; }
#pragma unroll
    for (int r = 0; r < 46; ++r) {
      float2 v = *(const float2*)&ins[r][2 * f];
#pragma unroll
      for (int t = 0; t < 8; ++t) {
        const int kt = r - 2 * t;   // compile-time per (r,t)
        if (kt >= 0 && kt < 32) {
          accA[t] = fmaf(v.x, wA[2 * kt], accA[t]);
          accA[t] = fmaf(v.y, wA[2 * kt + 1], accA[t]);
          accB[t] = fmaf(v.x, wB[2 * kt], accB[t]);
          accB[t] = fmaf(v.y, wB[2 * kt + 1], accB[t]);
        }
      }
    }
#pragma unroll
    for (int t = 0; t < 8; ++t) {
      if (t < T) {
        float a = accA[t] > 0.0f ? accA[t] : 0.0f;
        float bb = accB[t] > 0.0f ? accB[t] : 0.0f;
        unsigned int pk = (unsigned int)f2b(a) | ((unsigned int)f2b(bb) << 16);
        *(unsigned int*)&c1out[(((size_t)b * 241 + t0 + t) * 80 + f) * 32 + c0] = pk;
      }
    }
  }
}

// ---------------- conv2 v3: LDS ring-buffer implicit GEMM --------------------------
__global__ __launch_bounds__(256) void conv2_kernel(
    const unsigned short* __restrict__ c1out, const unsigned short* __restrict__ wt2,
    const float* __restrict__ b2, unsigned short* __restrict__ X2) {
  __shared__ int ldsA[8 * 360 * 4];   // 8 slots x 360 16B-chunks = 46,080 B
  int tid = threadIdx.x;
  int lane = tid & 63, wave = tid >> 6;
  int quad = lane >> 4, l16 = lane & 15;
  int j = blockIdx.x;       // 0..14
  int b = blockIdx.y;       // 0..63

  int tlA[4], baseA[4];
#pragma unroll
  for (int mt = 0; mt < 4; ++mt) {
    int ml = wave * 64 + mt * 16 + l16;
    if (ml > 251) ml = 251;
    int tl = ml / 36;
    int f2 = ml - tl * 36;
    tlA[mt] = tl;
    baseA[mt] = (9 * f2 + quad) * 4;   // dword offset within slot at kf=0
  }
  const unsigned short* bp = wt2 + l16 * 32 + quad * 8;

  f32x4 zero = {0.f, 0.f, 0.f, 0.f};
  f32x4 acc[4][2];
#pragma unroll
  for (int mt = 0; mt < 4; ++mt) {
    acc[mt][0] = zero;
    acc[mt][1] = zero;
  }

  const size_t rowsh = 2560;  // shorts per t-row (80*32)
  const unsigned short* gbase = c1out + ((size_t)b * 241 + 14 * j) * rowsh;

  for (int p = 0; p < 2; ++p) {
#pragma unroll
    for (int k = 0; k < 9; ++k) {
      int i = tid + 256 * k;
      if (i < 2240) {
        int h = i / 320, r = i - 320 * h;
        int4 v = *(const int4*)(gbase + (size_t)(p + 2 * h) * rowsh + r * 8);
        *((int4*)&ldsA[(h * 360 + r + (r >> 3)) * 4]) = v;
      }
    }
    for (int k = 0; k < 16; ++k) {
      int kt = 2 * k + p;
      if (k > 0) {
        int slot = (k + 6) & 7;
        const unsigned short* g = gbase + (size_t)(p + 2 * (k + 6)) * rowsh;
        int r = tid;
        int4 v = *(const int4*)(g + r * 8);
        *((int4*)&ldsA[(slot * 360 + r + (r >> 3)) * 4]) = v;
        if (tid < 64) {
          int r2 = 256 + tid;
          int4 v2 = *(const int4*)(g + r2 * 8);
          *((int4*)&ldsA[(slot * 360 + r2 + (r2 >> 3)) * 4]) = v2;
        }
      }
      __syncthreads();
      const unsigned short* bk = bp + (size_t)kt * 9216;
#pragma unroll
      for (int kf = 0; kf < 9; ++kf) {
        s16x8 b0 = *(const s16x8*)(bk + kf * 1024);
        s16x8 b1v = *(const s16x8*)(bk + kf * 1024 + 512);
        int kfo = (4 * kf + (kf >> 1)) * 4;
#pragma unroll
        for (int mt = 0; mt < 4; ++mt) {
          int slot = (k + tlA[mt]) & 7;
          s16x8 a = *(const s16x8*)&ldsA[slot * 1440 + baseA[mt] + kfo];
          acc[mt][0] = __builtin_amdgcn_mfma_f32_16x16x32_bf16(a, b0, acc[mt][0], 0, 0, 0);
          acc[mt][1] = __builtin_amdgcn_mfma_f32_16x16x32_bf16(a, b1v, acc[mt][1], 0, 0, 0);
        }
      }
    }
    __syncthreads();
  }

#pragma unroll
  for (int nt = 0; nt < 2; ++nt) {
    int n = nt * 16 + l16;
    float bias = b2[n];
#pragma unroll
    for (int mt = 0; mt < 4; ++mt) {
      f32x4 v = acc[mt][nt];
#pragma unroll
      for (int r = 0; r < 4; ++r) {
        int ml = wave * 64 + mt * 16 + quad * 4 + r;
        if (ml < 252) {
          int tl = ml / 36;
          int f2 = ml - tl * 36;
          int t2 = 7 * j + tl;
          float val = v[r] + bias;
          val = val > 0.0f ? val : 0.0f;
          X2[((size_t)(b * 105 + t2) * 32 + n) * 36 + f2] = f2b(val);
        }
      }
    }
  }
}

// ---------------- xp GEMM: xp[(b,t2)][j] = X2 @ w_ih^T + b_ih, M=6720,N=384,K=1152 ---
__global__ __launch_bounds__(256) void xp_kernel(
    const unsigned short* __restrict__ X2, const unsigned short* __restrict__ wihB,
    const float* __restrict__ bih, float* __restrict__ xp) {
  int tid = threadIdx.x;
  int lane = tid & 63, wave = tid >> 6;
  int quad = lane >> 4, l16 = lane & 15;
  int m_tile = blockIdx.x * 4 + wave;   // 0..419
  int n0 = blockIdx.y * 128;
  int row = m_tile * 16 + l16;
  const unsigned short* apb = X2 + (size_t)row * 1152 + quad * 8;
  const unsigned short* bpb = wihB + (size_t)(n0 + l16) * 1152 + quad * 8;
  f32x4 zero = {0.f, 0.f, 0.f, 0.f};
  f32x4 acc[8];
#pragma unroll
  for (int nt = 0; nt < 8; ++nt) acc[nt] = zero;
  for (int ks = 0; ks < 36; ++ks) {
    s16x8 a = *(const s16x8*)(apb + ks * 32);
#pragma unroll
    for (int nt = 0; nt < 8; ++nt) {
      s16x8 bb = *(const s16x8*)(bpb + (size_t)nt * 16 * 1152 + ks * 32);
      acc[nt] = __builtin_amdgcn_mfma_f32_16x16x32_bf16(a, bb, acc[nt], 0, 0, 0);
    }
  }
#pragma unroll
  for (int nt = 0; nt < 8; ++nt) {
    int n = n0 + nt * 16 + l16;
    float bias = bih[n];
#pragma unroll
    for (int r = 0; r < 4; ++r) {
      int m = m_tile * 16 + quad * 4 + r;
      xp[(size_t)m * 384 + n] = acc[nt][r] + bias;
    }
  }
}

// ---------------- encoder GRU v2: 384 thr, reg weights, prefetched xp ---------------
__global__ __launch_bounds__(384) void enc_kernel(
    const float* __restrict__ xp, const unsigned int* __restrict__ wpe,
    const float* __restrict__ bhh, float* __restrict__ eh) {
  __shared__ float h_s[128];
  __shared__ float gh_s[384];
  int tid = threadIdx.x, b = blockIdx.x;
  unsigned int w[64];
#pragma unroll
  for (int k2 = 0; k2 < 64; ++k2) w[k2] = wpe[k2 * 384 + tid];
  if (tid < 128) h_s[tid] = 0.0f;
  float bias = bhh[tid];
  __syncthreads();
  const float* xpb = xp + (size_t)b * 105 * 384;
  for (int t = 0; t < 105; ++t) {
    const float* xpt = xpb + (size_t)t * 384;
    float xg = 0.0f, xn = 0.0f;              // prefetch (hides L2 under GEMV)
    if (tid < 256) xg = xpt[tid];
    if (tid < 128) xn = xpt[tid + 256];
    float acc = bias;
#pragma unroll
    for (int k2 = 0; k2 < 64; ++k2) {
      unsigned int wv = w[k2];
      float2 h2 = *(const float2*)&h_s[2 * k2];
      acc = fmaf(h2.x, __uint_as_float(wv << 16), acc);
      acc = fmaf(h2.y, __uint_as_float(wv & 0xffff0000u), acc);
    }
    gh_s[tid] = (tid < 256) ? sigmoidf_(xg + acc) : acc;
    __syncthreads();
    if (tid < 128) {
      float r = gh_s[tid];
      float z = gh_s[tid + 128];
      float hnp = gh_s[tid + 256];
      float nn = tanhf_(xn + r * hnp);
      float hn = (1.0f - z) * nn + z * h_s[tid];
      h_s[tid] = hn;
      eh[((size_t)b * 105 + t) * 128 + tid] = hn;
    }
    __syncthreads();
  }
}

// ---------------- ip: emb[y] @ dec_w_ih^T + b ---------------------------------------
__global__ __launch_bounds__(384) void ip_kernel(
    const int* __restrict__ y, const float* __restrict__ emb,
    const float* __restrict__ wdT, const float* __restrict__ dbih,
    float* __restrict__ ipg) {
  __shared__ float er[32];
  int bs = blockIdx.x;
  int b = bs / 63, s = bs - b * 63;
  int tid = threadIdx.x;
  if (tid < 32) er[tid] = emb[(size_t)y[b * 64 + s] * 32 + tid];
  __syncthreads();
  float acc = dbih[tid];
#pragma unroll
  for (int e = 0; e < 32; ++e) acc = fmaf(er[e], wdT[e * 384 + tid], acc);
  ipg[(size_t)bs * 384 + tid] = acc;
}

// ---------------- decoder v3: 384 thr, 64 reg-weights/thr, split chains -------------
__global__ __launch_bounds__(384) void dec_kernel(
    const float* __restrict__ eh, const float* __restrict__ ipg,
    const unsigned int* __restrict__ wpd, const float* __restrict__ dbhh,
    const float* __restrict__ fcw, const float* __restrict__ fcb,
    float* __restrict__ outg) {
  __shared__ float eh_s[105 * 132];   // pitch 132: 16B-aligned rows
  __shared__ float gh_s[384];
  __shared__ float hx_s[128];
  __shared__ float hx2_s[128];
  __shared__ float s_s[112];
  __shared__ float a_s[112];
  __shared__ float red_s[2];
  int tid = threadIdx.x, b = blockIdx.x;

  unsigned int w[64];                 // w_hh row `tid` (packed bf16x2)
#pragma unroll
  for (int k2 = 0; k2 < 64; ++k2) w[k2] = wpd[k2 * 384 + tid];
  float bias = dbhh[tid];

  float wf[16];                       // fc weights: v=tid>>3, part=tid&7
  float fcbv = 0.0f;
  if (tid < 256) {
    int v = tid >> 3, part = tid & 7;
#pragma unroll
    for (int d = 0; d < 16; ++d) wf[d] = fcw[v * 128 + part * 16 + d];
    fcbv = fcb[v];
  }

  // stage eh (float4, coalesced)
  for (int i = tid; i < 105 * 32; i += 384) {
    int t = i >> 5, d4 = i & 31;
    *(float4*)&eh_s[t * 132 + d4 * 4] =
        *(const float4*)(eh + ((size_t)b * 105 + t) * 128 + d4 * 4);
  }
  if (tid < 128) hx_s[tid] = 0.0f;
  __syncthreads();

  const float* ipb = ipg + (size_t)b * 63 * 384;
  for (int s = 0; s < 63; ++s) {
    const float* ipt = ipb + (size_t)s * 384;
    float xg = 0.0f, xn = 0.0f;          // prefetch: L2 latency hides under GEMV
    if (tid < 256) xg = ipt[tid];
    if (tid < 128) xn = ipt[tid + 256];

    // ---- GEMV: gh[tid] = <hx, w_hh[tid]> + b_hh[tid] ----
    float acc = bias;
#pragma unroll
    for (int k2 = 0; k2 < 64; ++k2) {
      unsigned int wv = w[k2];
      float2 h2 = *(const float2*)&hx_s[2 * k2];
      acc = fmaf(h2.x, __uint_as_float(wv << 16), acc);
      acc = fmaf(h2.y, __uint_as_float(wv & 0xffff0000u), acc);
    }
    gh_s[tid] = (tid < 256) ? sigmoidf_(xg + acc) : acc;
    __syncthreads();                     // (1) gh ready

    // ---- gate math -> hx2 ----
    if (tid < 128) {
      float r = gh_s[tid];
      float z = gh_s[tid + 128];
      float hnp = gh_s[tid + 256];
      float nn = tanhf_(xn + r * hnp);
      hx2_s[tid] = (1.0f - z) * nn + z * hx_s[tid];
    }
    __syncthreads();                     // (2) hx2 ready

    // ---- scores: 105 rows x 2 K-parts ----
    {
      float sc = 0.0f;
      int row = tid >> 1, part = tid & 1;
      if (tid < 210) {
        const float* ehrow = &eh_s[row * 132 + part * 64];
        const float* hxp = &hx2_s[part * 64];
#pragma unroll
        for (int d4 = 0; d4 < 16; ++d4) {
          float4 e4 = *(const float4*)&ehrow[4 * d4];
          float4 h4 = *(const float4*)&hxp[4 * d4];
          sc = fmaf(e4.x, h4.x, fmaf(e4.y, h4.y, fmaf(e4.z, h4.z, fmaf(e4.w, h4.w, sc))));
        }
      }
      sc += __shfl_xor(sc, 1);
      if (tid < 210 && part == 0) s_s[row] = sc;
    }
    __syncthreads();                     // (3) s_s ready

    // ---- softmax (wave 0 only) ----
    if (tid < 64) {
      float s0 = s_s[tid];
      float s1 = (tid < 41) ? s_s[tid + 64] : -1e30f;
      float m = fmaxf(s0, s1);
#pragma unroll
      for (int off = 32; off > 0; off >>= 1) m = fmaxf(m, __shfl_xor(m, off));
      float e0 = __expf(s0 - m);
      float e1 = (tid < 41) ? __expf(s1 - m) : 0.0f;
      a_s[tid] = e0;
      if (tid < 41) a_s[tid + 64] = e1;
      float sum = e0 + e1;
#pragma unroll
      for (int off = 32; off > 0; off >>= 1) sum += __shfl_xor(sum, off);
      if (tid == 0) red_s[0] = 1.0f / sum;
    }
    __syncthreads();                     // (4) a_s + rsum ready
    float rsum = red_s[0];

    // ---- ctx: 128 d x 2 t-parts -> hx ----
    if (tid < 256) {
      int d = tid >> 1, p = tid & 1;
      int t0 = p ? 53 : 0, t1 = p ? 105 : 53;
      float c = 0.0f;
      for (int t = t0; t < t1; ++t) c = fmaf(a_s[t], eh_s[t * 132 + d], c);
      c += __shfl_xor(c, 1);
      if (p == 0) hx_s[d] = c * rsum;
    }
    __syncthreads();                     // (5) hx (ctx) ready

    // ---- fc: 32 v x 8 parts ----
    if (tid < 256) {
      int part = tid & 7;
      float p = 0.0f;
      const float* cx = &hx_s[part * 16];
#pragma unroll
      for (int d = 0; d < 16; ++d) p = fmaf(cx[d], wf[d], p);
      p += __shfl_xor(p, 1);
      p += __shfl_xor(p, 2);
      p += __shfl_xor(p, 4);
      if (part == 0) outg[((size_t)b * 63 + s) * 32 + (tid >> 3)] = fcbv + p;
    }
  }
}

extern "C" void kernel_launch(void* const* d_in, const int* in_sizes, int n_in,
                              void* d_out, int out_size, void* d_ws, size_t ws_size,
                              hipStream_t stream) {
  const float* x = (const float*)d_in[0];
  const int* y = (const int*)d_in[1];
  const float* mean = (const float*)d_in[2];
  const float* stdv = (const float*)d_in[3];
  const float* w1 = (const float*)d_in[4];
  const float* b1 = (const float*)d_in[5];
  const float* w2 = (const float*)d_in[6];
  const float* b2 = (const float*)d_in[7];
  const float* wih = (const float*)d_in[8];
  const float* whh = (const float*)d_in[9];
  const float* bih = (const float*)d_in[10];
  const float* bhh = (const float*)d_in[11];
  const float* emb = (const float*)d_in[12];
  const float* dwih = (const float*)d_in[13];
  const float* dwhh = (const float*)d_in[14];
  const float* dbih = (const float*)d_in[15];
  const float* dbhh = (const float*)d_in[16];
  const float* fcw = (const float*)d_in[17];
  const float* fcb = (const float*)d_in[18];
  float* out = (float*)d_out;
  char* ws = (char*)d_ws;

  // ws layout (bytes); xp/eh/ip overlap dead c1out region (xp runs after conv2).
  unsigned short* c1out = (unsigned short*)(ws + 0);              // 78,970,880 B
  float* xp = (float*)(ws + 0);                                   // 10,321,920 B (after conv2)
  float* eh = (float*)(ws + 10321920);                            //  3,440,640 B
  float* ipg = (float*)(ws + 13762560);                           //  6,193,152 B
  unsigned short* wt2 = (unsigned short*)(ws + 78970880);         //    589,824 B
  unsigned short* wihB = (unsigned short*)(ws + 79560704);        //    884,736 B
  unsigned int* wpe = (unsigned int*)(ws + 80445440);             //     98,304 B
  unsigned int* wpd = (unsigned int*)(ws + 80543744);             //     98,304 B
  float* wdT = (float*)(ws + 80642048);                           //     49,152 B
  unsigned short* X2 = (unsigned short*)(ws + 80691200);          // 15,482,880 B

  prep_kernel<<<3120, 256, 0, stream>>>(w2, wih, whh, dwhh, dwih, wt2, wihB, wpe, wpd, wdT);
  conv1_kernel<<<dim3(31, 64), 256, 0, stream>>>(x, mean, stdv, w1, b1, c1out);
  conv2_kernel<<<dim3(15, 64), 256, 0, stream>>>(c1out, wt2, b2, X2);
  xp_kernel<<<dim3(105, 3), 256, 0, stream>>>(X2, wihB, bih, xp);
  ip_kernel<<<64 * 63, 384, 0, stream>>>(y, emb, wdT, dbih, ipg);
  enc_kernel<<<64, 384, 0, stream>>>(xp, wpe, bhh, eh);
  dec_kernel<<<64, 384, 0, stream>>>(eh, ipg, wpd, dbhh, fcw, fcb, out);
}

// Round 7
// 939.839 us; speedup vs baseline: 1.8633x; 1.0631x over previous
//
#include <hip/hip_runtime.h>

// Model: conv(32x2,s2) -> conv(32x9,s2) -> GRU encoder (105 steps) ->
//        attention decoder (63 steps) -> fc.  B=64,H=128,V=32.

typedef float f32x4 __attribute__((ext_vector_type(4)));
typedef short s16x8 __attribute__((ext_vector_type(8)));

static __device__ __forceinline__ unsigned short f2b(float f) {
  unsigned int u = __float_as_uint(f);
  unsigned int r = u + 0x7fffu + ((u >> 16) & 1u);
  return (unsigned short)(r >> 16);
}
static __device__ __forceinline__ float sigmoidf_(float x) {
  return 1.0f / (1.0f + __expf(-x));
}
static __device__ __forceinline__ float tanhf_(float x) {
  float ax = fabsf(x);
  float t = __expf(-2.0f * ax);
  float r = (1.0f - t) / (1.0f + t);
  return x >= 0.0f ? r : -r;
}
static __device__ __forceinline__ float blo(unsigned int w) {
  return __uint_as_float(w << 16);
}
static __device__ __forceinline__ float bhi(unsigned int w) {
  return __uint_as_float(w & 0xffff0000u);
}

// ---------------- weight pre-transforms (re-run every launch; ws is re-poisoned) ----
__global__ __launch_bounds__(256) void prep_kernel(
    const float* __restrict__ w2, const float* __restrict__ wih,
    const float* __restrict__ whh, const float* __restrict__ dwhh,
    const float* __restrict__ dwih,
    unsigned short* __restrict__ wt2, unsigned short* __restrict__ wihB,
    unsigned int* __restrict__ wpe, unsigned int* __restrict__ wpd,
    float* __restrict__ wdT) {
  int idx = blockIdx.x * 256 + threadIdx.x;
  if (idx < 294912) {
    int ci = idx & 31;
    int n = (idx >> 5) & 31;
    int kk = idx >> 10;          // kt*9+kf
    int kf = kk % 9, kt = kk / 9;
    wt2[idx] = f2b(w2[((n * 32 + ci) * 32 + kt) * 9 + kf]);
  } else if (idx < 737280) {
    int i = idx - 294912;
    wihB[i] = f2b(wih[i]);
  } else if (idx < 761856) {
    int i = idx - 737280;
    int j = i % 384, k2 = i / 384;
    unsigned int lo = f2b(whh[j * 128 + 2 * k2]);
    unsigned int hi = f2b(whh[j * 128 + 2 * k2 + 1]);
    wpe[i] = lo | (hi << 16);
  } else if (idx < 786432) {
    int i = idx - 761856;
    int j = i % 384, k2 = i / 384;
    unsigned int lo = f2b(dwhh[j * 128 + 2 * k2]);
    unsigned int hi = f2b(dwhh[j * 128 + 2 * k2 + 1]);
    wpd[i] = lo | (hi << 16);
  } else if (idx < 798720) {
    int i = idx - 786432;
    int j = i % 384, e = i / 384;
    wdT[i] = dwih[j * 32 + e];
  }
}

// ---------------- conv1 v2: row-reuse register-blocked, out [b][t][f][c] bf16 -------
__global__ __launch_bounds__(256) void conv1_kernel(
    const float* __restrict__ x, const float* __restrict__ mean,
    const float* __restrict__ stdv, const float* __restrict__ w1,
    const float* __restrict__ b1, unsigned short* __restrict__ c1out) {
  __shared__ float ins[46][162];
  __shared__ float meanL[161];
  __shared__ float rstdL[161];
  int tid = threadIdx.x;
  int tt = blockIdx.x;        // 0..30
  int b = blockIdx.y;         // 0..63
  int t0 = tt * 8;
  if (tid < 161) {
    meanL[tid] = mean[tid];
    rstdL[tid] = 1.0f / stdv[tid];
  }
  int fs = tid >> 4, cg = tid & 15;
  int c0 = 2 * cg;
  float wA[64], wB[64];
  {
    const float4* wa = (const float4*)(w1 + c0 * 64);
    const float4* wb = (const float4*)(w1 + (c0 + 1) * 64);
#pragma unroll
    for (int i = 0; i < 16; ++i) {
      float4 va = wa[i], vb = wb[i];
      wA[4 * i] = va.x; wA[4 * i + 1] = va.y; wA[4 * i + 2] = va.z; wA[4 * i + 3] = va.w;
      wB[4 * i] = vb.x; wB[4 * i + 1] = vb.y; wB[4 * i + 2] = vb.z; wB[4 * i + 3] = vb.w;
    }
  }
  float biasA = b1[c0], biasB = b1[c0 + 1];
  __syncthreads();   // meanL/rstdL ready

  const float* xb = x + ((size_t)b * 512 + 2 * t0) * 161;
  int nrows = 512 - 2 * t0; if (nrows > 46) nrows = 46;
  for (int i = tid; i < 46 * 161; i += 256) {
    int r = i / 161, col = i - r * 161;
    float v = (r < nrows) ? xb[(size_t)r * 161 + col] : 0.0f;
    ins[r][col] = (v - meanL[col]) * rstdL[col];
  }
  __syncthreads();

  int T = 241 - t0; if (T > 8) T = 8;
#pragma unroll
  for (int fi = 0; fi < 5; ++fi) {
    int f = fs + 16 * fi;
    float accA[8], accB[8];
#pragma unroll
    for (int t = 0; t < 8; ++t) { accA[t] = biasA; accB[t] = biasB; }
#pragma unroll
    for (int r = 0; r < 46; ++r) {
      float2 v = *(const float2*)&ins[r][2 * f];
#pragma unroll
      for (int t = 0; t < 8; ++t) {
        const int kt = r - 2 * t;
        if (kt >= 0 && kt < 32) {
          accA[t] = fmaf(v.x, wA[2 * kt], accA[t]);
          accA[t] = fmaf(v.y, wA[2 * kt + 1], accA[t]);
          accB[t] = fmaf(v.x, wB[2 * kt], accB[t]);
          accB[t] = fmaf(v.y, wB[2 * kt + 1], accB[t]);
        }
      }
    }
#pragma unroll
    for (int t = 0; t < 8; ++t) {
      if (t < T) {
        float a = accA[t] > 0.0f ? accA[t] : 0.0f;
        float bb = accB[t] > 0.0f ? accB[t] : 0.0f;
        unsigned int pk = (unsigned int)f2b(a) | ((unsigned int)f2b(bb) << 16);
        *(unsigned int*)&c1out[(((size_t)b * 241 + t0 + t) * 80 + f) * 32 + c0] = pk;
      }
    }
  }
}

// ---------------- conv2 v3: LDS ring-buffer implicit GEMM --------------------------
__global__ __launch_bounds__(256) void conv2_kernel(
    const unsigned short* __restrict__ c1out, const unsigned short* __restrict__ wt2,
    const float* __restrict__ b2, unsigned short* __restrict__ X2) {
  __shared__ int ldsA[8 * 360 * 4];   // 8 slots x 360 16B-chunks = 46,080 B
  int tid = threadIdx.x;
  int lane = tid & 63, wave = tid >> 6;
  int quad = lane >> 4, l16 = lane & 15;
  int j = blockIdx.x;       // 0..14
  int b = blockIdx.y;       // 0..63

  int tlA[4], baseA[4];
#pragma unroll
  for (int mt = 0; mt < 4; ++mt) {
    int ml = wave * 64 + mt * 16 + l16;
    if (ml > 251) ml = 251;
    int tl = ml / 36;
    int f2 = ml - tl * 36;
    tlA[mt] = tl;
    baseA[mt] = (9 * f2 + quad) * 4;
  }
  const unsigned short* bp = wt2 + l16 * 32 + quad * 8;

  f32x4 zero = {0.f, 0.f, 0.f, 0.f};
  f32x4 acc[4][2];
#pragma unroll
  for (int mt = 0; mt < 4; ++mt) {
    acc[mt][0] = zero;
    acc[mt][1] = zero;
  }

  const size_t rowsh = 2560;  // shorts per t-row (80*32)
  const unsigned short* gbase = c1out + ((size_t)b * 241 + 14 * j) * rowsh;

  for (int p = 0; p < 2; ++p) {
#pragma unroll
    for (int k = 0; k < 9; ++k) {
      int i = tid + 256 * k;
      if (i < 2240) {
        int h = i / 320, r = i - 320 * h;
        int4 v = *(const int4*)(gbase + (size_t)(p + 2 * h) * rowsh + r * 8);
        *((int4*)&ldsA[(h * 360 + r + (r >> 3)) * 4]) = v;
      }
    }
    for (int k = 0; k < 16; ++k) {
      int kt = 2 * k + p;
      if (k > 0) {
        int slot = (k + 6) & 7;
        const unsigned short* g = gbase + (size_t)(p + 2 * (k + 6)) * rowsh;
        int r = tid;
        int4 v = *(const int4*)(g + r * 8);
        *((int4*)&ldsA[(slot * 360 + r + (r >> 3)) * 4]) = v;
        if (tid < 64) {
          int r2 = 256 + tid;
          int4 v2 = *(const int4*)(g + r2 * 8);
          *((int4*)&ldsA[(slot * 360 + r2 + (r2 >> 3)) * 4]) = v2;
        }
      }
      __syncthreads();
      const unsigned short* bk = bp + (size_t)kt * 9216;
#pragma unroll
      for (int kf = 0; kf < 9; ++kf) {
        s16x8 b0 = *(const s16x8*)(bk + kf * 1024);
        s16x8 b1v = *(const s16x8*)(bk + kf * 1024 + 512);
        int kfo = (4 * kf + (kf >> 1)) * 4;
#pragma unroll
        for (int mt = 0; mt < 4; ++mt) {
          int slot = (k + tlA[mt]) & 7;
          s16x8 a = *(const s16x8*)&ldsA[slot * 1440 + baseA[mt] + kfo];
          acc[mt][0] = __builtin_amdgcn_mfma_f32_16x16x32_bf16(a, b0, acc[mt][0], 0, 0, 0);
          acc[mt][1] = __builtin_amdgcn_mfma_f32_16x16x32_bf16(a, b1v, acc[mt][1], 0, 0, 0);
        }
      }
    }
    __syncthreads();
  }

#pragma unroll
  for (int nt = 0; nt < 2; ++nt) {
    int n = nt * 16 + l16;
    float bias = b2[n];
#pragma unroll
    for (int mt = 0; mt < 4; ++mt) {
      f32x4 v = acc[mt][nt];
#pragma unroll
      for (int r = 0; r < 4; ++r) {
        int ml = wave * 64 + mt * 16 + quad * 4 + r;
        if (ml < 252) {
          int tl = ml / 36;
          int f2 = ml - tl * 36;
          int t2 = 7 * j + tl;
          float val = v[r] + bias;
          val = val > 0.0f ? val : 0.0f;
          X2[((size_t)(b * 105 + t2) * 32 + n) * 36 + f2] = f2b(val);
        }
      }
    }
  }
}

// ---------------- xp GEMM: xp[(b,t2)][j] = X2 @ w_ih^T + b_ih, M=6720,N=384,K=1152 ---
__global__ __launch_bounds__(256) void xp_kernel(
    const unsigned short* __restrict__ X2, const unsigned short* __restrict__ wihB,
    const float* __restrict__ bih, float* __restrict__ xp) {
  int tid = threadIdx.x;
  int lane = tid & 63, wave = tid >> 6;
  int quad = lane >> 4, l16 = lane & 15;
  int m_tile = blockIdx.x * 4 + wave;   // 0..419
  int n0 = blockIdx.y * 128;
  int row = m_tile * 16 + l16;
  const unsigned short* apb = X2 + (size_t)row * 1152 + quad * 8;
  const unsigned short* bpb = wihB + (size_t)(n0 + l16) * 1152 + quad * 8;
  f32x4 zero = {0.f, 0.f, 0.f, 0.f};
  f32x4 acc[8];
#pragma unroll
  for (int nt = 0; nt < 8; ++nt) acc[nt] = zero;
  for (int ks = 0; ks < 36; ++ks) {
    s16x8 a = *(const s16x8*)(apb + ks * 32);
#pragma unroll
    for (int nt = 0; nt < 8; ++nt) {
      s16x8 bb = *(const s16x8*)(bpb + (size_t)nt * 16 * 1152 + ks * 32);
      acc[nt] = __builtin_amdgcn_mfma_f32_16x16x32_bf16(a, bb, acc[nt], 0, 0, 0);
    }
  }
#pragma unroll
  for (int nt = 0; nt < 8; ++nt) {
    int n = n0 + nt * 16 + l16;
    float bias = bih[n];
#pragma unroll
    for (int r = 0; r < 4; ++r) {
      int m = m_tile * 16 + quad * 4 + r;
      xp[(size_t)m * 384 + n] = acc[nt][r] + bias;
    }
  }
}

// ---------------- ip: emb[y] @ dec_w_ih^T + b ---------------------------------------
__global__ __launch_bounds__(384) void ip_kernel(
    const int* __restrict__ y, const float* __restrict__ emb,
    const float* __restrict__ wdT, const float* __restrict__ dbih,
    float* __restrict__ ipg) {
  __shared__ float er[32];
  int bs = blockIdx.x;
  int b = bs / 63, s = bs - b * 63;
  int tid = threadIdx.x;
  if (tid < 32) er[tid] = emb[(size_t)y[b * 64 + s] * 32 + tid];
  __syncthreads();
  float acc = dbih[tid];
#pragma unroll
  for (int e = 0; e < 32; ++e) acc = fmaf(er[e], wdT[e * 384 + tid], acc);
  ipg[(size_t)bs * 384 + tid] = acc;
}

// ---------------- fused RNN: encoder (105) + attention decoder (63), 64 blocks ------
// eh lives ONLY in LDS as ehT[d][t] (pitch 116): scores read columns (stride-1 lanes,
// conflict-free), ctx reads rows via b128. ip/xp gate inputs software-pipelined.
__global__ __launch_bounds__(384) void rnn_kernel(
    const float* __restrict__ xp, const unsigned int* __restrict__ wpe,
    const float* __restrict__ bhh, const float* __restrict__ ipg,
    const unsigned int* __restrict__ wpd, const float* __restrict__ dbhh,
    const float* __restrict__ fcw, const float* __restrict__ fcb,
    float* __restrict__ outg) {
  __shared__ __align__(16) float ehT[128 * 116];   // 59,392 B
  __shared__ __align__(16) float gh_s[384];
  __shared__ __align__(16) float h_s[128];
  __shared__ __align__(16) float hx2_s[128];
  __shared__ float s_s[112];
  __shared__ __align__(16) float a_s[112];
  __shared__ float red_s[1];
  int tid = threadIdx.x, b = blockIdx.x;

  // ================= encoder =================
  unsigned int w[64];
#pragma unroll
  for (int k2 = 0; k2 < 64; ++k2) w[k2] = wpe[k2 * 384 + tid];
  float bias = bhh[tid];
  if (tid < 128) h_s[tid] = 0.0f;
  if (tid < 112) a_s[tid] = 0.0f;            // pad cols 105..111 stay 0 forever
  for (int i = tid; i < 128 * 11; i += 384) { // zero ehT pad t=105..115
    int d = i / 11, t = 105 + i - (i / 11) * 11;
    ehT[d * 116 + t] = 0.0f;
  }
  __syncthreads();

  const float* xpb = xp + (size_t)b * 105 * 384;
  float nxg = (tid < 256) ? xpb[tid] : 0.0f;
  float nxn = (tid < 128) ? xpb[tid + 256] : 0.0f;
  for (int t = 0; t < 105; ++t) {
    float cxg = nxg, cxn = nxn;
    if (t < 104) {
      const float* xpt = xpb + (size_t)(t + 1) * 384;
      nxg = (tid < 256) ? xpt[tid] : 0.0f;
      nxn = (tid < 128) ? xpt[tid + 256] : 0.0f;
    }
    float a0 = bias, a1 = 0.0f;
#pragma unroll
    for (int k4 = 0; k4 < 32; ++k4) {
      float4 h4 = *(const float4*)&h_s[4 * k4];
      unsigned int wa = w[2 * k4], wb = w[2 * k4 + 1];
      a0 = fmaf(h4.x, blo(wa), a0);
      a1 = fmaf(h4.y, bhi(wa), a1);
      a0 = fmaf(h4.z, blo(wb), a0);
      a1 = fmaf(h4.w, bhi(wb), a1);
    }
    float acc = a0 + a1;
    gh_s[tid] = (tid < 256) ? sigmoidf_(cxg + acc) : acc;
    __syncthreads();
    if (tid < 128) {
      float r = gh_s[tid], z = gh_s[tid + 128], hnp = gh_s[tid + 256];
      float nn = tanhf_(cxn + r * hnp);
      float hn = (1.0f - z) * nn + z * h_s[tid];
      h_s[tid] = hn;
      ehT[tid * 116 + t] = hn;
    }
    __syncthreads();
  }

  // ================= decoder =================
#pragma unroll
  for (int k2 = 0; k2 < 64; ++k2) w[k2] = wpd[k2 * 384 + tid];
  bias = dbhh[tid];
  float wf[32];
  float fcbv = 0.0f;
  int fv = 0, fp = 0;
  if (tid >= 256) {
    int i = tid - 256;
    fp = i & 3; fv = i >> 2;
#pragma unroll
    for (int d = 0; d < 32; ++d) wf[d] = fcw[fv * 128 + fp * 32 + d];
    fcbv = fcb[fv];
  }
  if (tid < 128) h_s[tid] = 0.0f;
  __syncthreads();

  const float* ipb = ipg + (size_t)b * 63 * 384;
  nxg = (tid < 256) ? ipb[tid] : 0.0f;
  nxn = (tid < 128) ? ipb[tid + 256] : 0.0f;
  for (int s = 0; s < 63; ++s) {
    float cxg = nxg, cxn = nxn;
    if (s < 62) {
      const float* ipt = ipb + (size_t)(s + 1) * 384;
      nxg = (tid < 256) ? ipt[tid] : 0.0f;
      nxn = (tid < 128) ? ipt[tid + 256] : 0.0f;
    }
    // ---- GEMV ----
    float a0 = bias, a1 = 0.0f;
#pragma unroll
    for (int k4 = 0; k4 < 32; ++k4) {
      float4 h4 = *(const float4*)&h_s[4 * k4];
      unsigned int wa = w[2 * k4], wb = w[2 * k4 + 1];
      a0 = fmaf(h4.x, blo(wa), a0);
      a1 = fmaf(h4.y, bhi(wa), a1);
      a0 = fmaf(h4.z, blo(wb), a0);
      a1 = fmaf(h4.w, bhi(wb), a1);
    }
    float acc = a0 + a1;
    gh_s[tid] = (tid < 256) ? sigmoidf_(cxg + acc) : acc;
    __syncthreads();                     // (1) gh ready
    if (tid < 128) {
      float r = gh_s[tid], z = gh_s[tid + 128], hnp = gh_s[tid + 256];
      float nn = tanhf_(cxn + r * hnp);
      hx2_s[tid] = (1.0f - z) * nn + z * h_s[tid];
    }
    __syncthreads();                     // (2) hx2 ready

    // ---- scores: column reads of ehT (stride-1 lanes, conflict-free) ----
    if (tid < 210) {
      int row = tid >> 1, part = tid & 1;
      const float* ecol = &ehT[part * 64 * 116 + row];
      const float* hp = &hx2_s[part * 64];
      float s0 = 0.f, s1 = 0.f, s2 = 0.f, s3 = 0.f;
#pragma unroll 4
      for (int dd = 0; dd < 64; dd += 4) {
        s0 = fmaf(ecol[(dd + 0) * 116], hp[dd + 0], s0);
        s1 = fmaf(ecol[(dd + 1) * 116], hp[dd + 1], s1);
        s2 = fmaf(ecol[(dd + 2) * 116], hp[dd + 2], s2);
        s3 = fmaf(ecol[(dd + 3) * 116], hp[dd + 3], s3);
      }
      float sc = (s0 + s1) + (s2 + s3);
      sc += __shfl_xor(sc, 1);
      if (part == 0) s_s[row] = sc;
    }
    __syncthreads();                     // (3) s_s ready

    // ---- softmax (wave 0) ----
    if (tid < 64) {
      float v0 = s_s[tid];
      float v1 = (tid < 41) ? s_s[tid + 64] : -1e30f;
      float m = fmaxf(v0, v1);
#pragma unroll
      for (int off = 32; off > 0; off >>= 1) m = fmaxf(m, __shfl_xor(m, off));
      float e0 = __expf(v0 - m);
      float e1 = (tid < 41) ? __expf(v1 - m) : 0.0f;
      a_s[tid] = e0;
      if (tid < 41) a_s[tid + 64] = e1;
      float sum = e0 + e1;
#pragma unroll
      for (int off = 32; off > 0; off >>= 1) sum += __shfl_xor(sum, off);
      if (tid == 0) red_s[0] = 1.0f / sum;
    }
    __syncthreads();                     // (4) a_s + rsum ready
    float rsum = red_s[0];

    // ---- ctx: row reads of ehT via b128 (t padded to 112, a_s pad = 0) ----
    if (tid < 256) {
      int d = tid >> 1, half = tid & 1;
      const float* erow = &ehT[d * 116 + half * 56];
      const float* ap = &a_s[half * 56];
      float c0 = 0.f, c1 = 0.f, c2 = 0.f, c3 = 0.f;
#pragma unroll
      for (int jj = 0; jj < 14; ++jj) {
        float4 e4 = *(const float4*)&erow[4 * jj];
        float4 a4 = *(const float4*)&ap[4 * jj];
        c0 = fmaf(e4.x, a4.x, c0);
        c1 = fmaf(e4.y, a4.y, c1);
        c2 = fmaf(e4.z, a4.z, c2);
        c3 = fmaf(e4.w, a4.w, c3);
      }
      float c = (c0 + c1) + (c2 + c3);
      c += __shfl_xor(c, 1);
      if (half == 0) h_s[d] = c * rsum;  // carry = ctx
    }
    __syncthreads();                     // (5) hx (ctx) ready

    // ---- fc by threads 256..383 (off critical path; no extra barrier) ----
    if (tid >= 256) {
      const float* cx = &h_s[fp * 32];
      float p0 = 0.f, p1 = 0.f;
#pragma unroll
      for (int d = 0; d < 32; d += 2) {
        p0 = fmaf(cx[d], wf[d], p0);
        p1 = fmaf(cx[d + 1], wf[d + 1], p1);
      }
      float p = p0 + p1;
      p += __shfl_xor(p, 1);
      p += __shfl_xor(p, 2);
      if (fp == 0) outg[((size_t)b * 63 + s) * 32 + fv] = fcbv + p;
    }
  }
}

extern "C" void kernel_launch(void* const* d_in, const int* in_sizes, int n_in,
                              void* d_out, int out_size, void* d_ws, size_t ws_size,
                              hipStream_t stream) {
  const float* x = (const float*)d_in[0];
  const int* y = (const int*)d_in[1];
  const float* mean = (const float*)d_in[2];
  const float* stdv = (const float*)d_in[3];
  const float* w1 = (const float*)d_in[4];
  const float* b1 = (const float*)d_in[5];
  const float* w2 = (const float*)d_in[6];
  const float* b2 = (const float*)d_in[7];
  const float* wih = (const float*)d_in[8];
  const float* whh = (const float*)d_in[9];
  const float* bih = (const float*)d_in[10];
  const float* bhh = (const float*)d_in[11];
  const float* emb = (const float*)d_in[12];
  const float* dwih = (const float*)d_in[13];
  const float* dwhh = (const float*)d_in[14];
  const float* dbih = (const float*)d_in[15];
  const float* dbhh = (const float*)d_in[16];
  const float* fcw = (const float*)d_in[17];
  const float* fcb = (const float*)d_in[18];
  float* out = (float*)d_out;
  char* ws = (char*)d_ws;

  // ws layout (bytes); xp/ip overlap dead c1out region (both written after conv2).
  unsigned short* c1out = (unsigned short*)(ws + 0);              // 78,970,880 B
  float* xp = (float*)(ws + 0);                                   // 10,321,920 B (after conv2)
  float* ipg = (float*)(ws + 13762560);                           //  6,193,152 B
  unsigned short* wt2 = (unsigned short*)(ws + 78970880);         //    589,824 B
  unsigned short* wihB = (unsigned short*)(ws + 79560704);        //    884,736 B
  unsigned int* wpe = (unsigned int*)(ws + 80445440);             //     98,304 B
  unsigned int* wpd = (unsigned int*)(ws + 80543744);             //     98,304 B
  float* wdT = (float*)(ws + 80642048);                           //     49,152 B
  unsigned short* X2 = (unsigned short*)(ws + 80691200);          // 15,482,880 B

  prep_kernel<<<3120, 256, 0, stream>>>(w2, wih, whh, dwhh, dwih, wt2, wihB, wpe, wpd, wdT);
  conv1_kernel<<<dim3(31, 64), 256, 0, stream>>>(x, mean, stdv, w1, b1, c1out);
  conv2_kernel<<<dim3(15, 64), 256, 0, stream>>>(c1out, wt2, b2, X2);
  xp_kernel<<<dim3(105, 3), 256, 0, stream>>>(X2, wihB, bih, xp);
  ip_kernel<<<64 * 63, 384, 0, stream>>>(y, emb, wdT, dbih, ipg);
  rnn_kernel<<<64, 384, 0, stream>>>(xp, wpe, bhh, ipg, wpd, dbhh, fcw, fcb, out);
}